// Round 1
// baseline (786.236 us; speedup 1.0000x reference)
//
#include <hip/hip_runtime.h>
#include <hip/hip_bf16.h>
#include <cstdint>
#include <cstddef>

// ---------------------------------------------------------------------------
// MGCN (2-layer relational GCN + linear head), bf16-MFMA implementation.
//
// Per layer:  agg[v] = sum_{e: dst=v} ((x[src]*rel[type]*norm[v]) @ W_dir)
//             h      = x + res * tanh(agg + x @ W_loop + b)
// Head:       out    = h2 @ mu_w + mu_b
//
// GEMMs use v_mfma_f32_16x16x32_bf16, 64-row tiles, full 256-col strip,
// 4 waves/block (each wave owns a 64-col strip).  W matrices are repacked
// once per call into MFMA-B-fragment-contiguous bf16 so the inner loop's
// B-loads are single coalesced 16B loads from L2.
// ---------------------------------------------------------------------------

typedef short bf16x8 __attribute__((ext_vector_type(8)));
typedef float f32x4  __attribute__((ext_vector_type(4)));

#define AP 264   // LDS A-tile pitch in bf16 elements (264 = 256 + 8 pad -> ~2-way banks)

__device__ __forceinline__ float b2f(unsigned short u) {
    union { unsigned u32; float f; } c; c.u32 = ((unsigned)u) << 16; return c.f;
}
__device__ __forceinline__ unsigned short f2b(float f) {
    union { float f; unsigned u; } c; c.f = f;
    unsigned r = c.u + 0x7FFFu + ((c.u >> 16) & 1u);   // RNE
    return (unsigned short)(r >> 16);
}

// ---- small prep kernels ----------------------------------------------------

__global__ void k_deg(const int* __restrict__ dst, float* __restrict__ deg, int E) {
    int i = blockIdx.x * blockDim.x + threadIdx.x;
    if (i < E) unsafeAtomicAdd(&deg[dst[i]], 1.0f);
}

__global__ void k_norm(float* __restrict__ deg, int N) {
    int i = blockIdx.x * blockDim.x + threadIdx.x;
    if (i < N) deg[i] = 1.0f / fmaxf(deg[i], 1.0f);
}

// f32 -> bf16, 4 elements / thread
__global__ void k_cvt4(const float* __restrict__ in, unsigned short* __restrict__ out, long n4) {
    long i = (long)blockIdx.x * blockDim.x + threadIdx.x;
    if (i < n4) {
        float4 v = ((const float4*)in)[i];
        ushort4 o;
        o.x = f2b(v.x); o.y = f2b(v.y); o.z = f2b(v.z); o.w = f2b(v.w);
        ((ushort4*)out)[i] = o;
    }
}

// Repack W[D][D] (row-major f32, k-major) into MFMA-B fragment layout bf16:
// out[((kk*16+nn)*64 + l)*8 + j] = W[kk*32 + (l>>4)*8 + j][nn*16 + (l&15)]
// (valid for D=256: kk in 0..7, nn in 0..15)
__global__ void k_wfrag(const float* __restrict__ W, unsigned short* __restrict__ out, int D) {
    int o = blockIdx.x * blockDim.x + threadIdx.x;
    if (o < D * D) {
        int j  = o & 7;
        int l  = (o >> 3) & 63;
        int nn = (o >> 9) & 15;
        int kk = o >> 13;
        int k = kk * 32 + (l >> 4) * 8 + j;
        int n = nn * 16 + (l & 15);
        out[o] = f2b(W[(size_t)k * D + n]);
    }
}

// ---- edge GEMM + atomic scatter -------------------------------------------
// Block = 64 edges x 256 cols.  half_E is a multiple of 64 so the W_in/W_out
// direction split falls on a block boundary.

__global__ __launch_bounds__(256, 2)
void k_edge(const unsigned short* __restrict__ xb,    // [N,D] bf16 node features
            const unsigned short* __restrict__ relb,  // [R,D] bf16 relation emb
            const int* __restrict__ src, const int* __restrict__ dst,
            const int* __restrict__ etype,
            const float* __restrict__ norm,           // [N] 1/max(deg,1)
            const unsigned short* __restrict__ WfIn,
            const unsigned short* __restrict__ WfOut,
            float* __restrict__ agg,                  // [N,D] f32 (atomic dest)
            int E, int halfE, int D)
{
    __shared__ unsigned short Alds[64 * AP];
    __shared__ int   sDst[64];
    __shared__ int   sSrc[64];
    __shared__ int   sTy[64];
    __shared__ float sNm[64];

    const int t = threadIdx.x;
    const int eBase = blockIdx.x * 64;
    const unsigned short* __restrict__ Wf = (eBase < halfE) ? WfIn : WfOut;

    if (t < 64) {
        int e = eBase + t;
        if (e < E) {
            int d0 = dst[e];
            sDst[t] = d0; sSrc[t] = src[e]; sTy[t] = etype[e]; sNm[t] = norm[d0];
        } else {
            sDst[t] = -1; sSrc[t] = 0; sTy[t] = 0; sNm[t] = 0.0f;
        }
    }
    __syncthreads();

    // stage A[r][c] = x[src[r]][c] * rel[type[r]][c] * norm[dst[r]]  (bf16)
    {
        const int r = t >> 2, q = t & 3;
        const unsigned short* xrow = xb   + (size_t)sSrc[r] * D;
        const unsigned short* rrow = relb + (size_t)sTy[r]  * D;
        const float nv = sNm[r];
        #pragma unroll
        for (int c8 = 0; c8 < 8; ++c8) {
            int col = q * 64 + c8 * 8;
            uint4 xv = *(const uint4*)(xrow + col);
            uint4 rv = *(const uint4*)(rrow + col);
            unsigned xs[4] = { xv.x, xv.y, xv.z, xv.w };
            unsigned rs[4] = { rv.x, rv.y, rv.z, rv.w };
            unsigned ov[4];
            #pragma unroll
            for (int p = 0; p < 4; ++p) {
                float f0 = b2f((unsigned short)(xs[p] & 0xffff)) * b2f((unsigned short)(rs[p] & 0xffff)) * nv;
                float f1 = b2f((unsigned short)(xs[p] >> 16))    * b2f((unsigned short)(rs[p] >> 16))    * nv;
                ov[p] = (unsigned)f2b(f0) | ((unsigned)f2b(f1) << 16);
            }
            *(uint4*)(&Alds[r * AP + col]) = make_uint4(ov[0], ov[1], ov[2], ov[3]);
        }
    }
    __syncthreads();

    const int w  = t >> 6;        // wave id: cols w*64 .. w*64+63
    const int l  = t & 63;
    const int lr = l & 15;
    const int lk = (l >> 4) * 8;

    f32x4 acc[4][4] = {};

    #pragma unroll
    for (int kk = 0; kk < 8; ++kk) {
        bf16x8 a[4], b[4];
        #pragma unroll
        for (int m = 0; m < 4; ++m)
            a[m] = *(const bf16x8*)(&Alds[(16 * m + lr) * AP + kk * 32 + lk]);
        #pragma unroll
        for (int n = 0; n < 4; ++n)
            b[n] = *(const bf16x8*)(Wf + (((size_t)(kk * 16 + (w * 4 + n)) * 64 + l) * 8));
        #pragma unroll
        for (int m = 0; m < 4; ++m)
            #pragma unroll
            for (int n = 0; n < 4; ++n)
                acc[m][n] = __builtin_amdgcn_mfma_f32_16x16x32_bf16(a[m], b[n], acc[m][n], 0, 0, 0);
    }

    // scatter: agg[dst[e]][col] += acc
    const int rb4 = (l >> 4) * 4;
    #pragma unroll
    for (int m = 0; m < 4; ++m) {
        #pragma unroll
        for (int i = 0; i < 4; ++i) {
            int r  = 16 * m + rb4 + i;
            int d0 = sDst[r];
            if (d0 >= 0) {
                float* arow = agg + (size_t)d0 * D + w * 64 + lr;
                #pragma unroll
                for (int n = 0; n < 4; ++n)
                    unsafeAtomicAdd(arow + 16 * n, acc[m][n][i]);
            }
        }
    }
}

// ---- node GEMM (x @ W) with fused epilogue --------------------------------
// mode 0: layer   ->  h = xres + res * tanh(acc + agg + bias); write outF/outB
// mode 1: head    ->  outF = acc + bias

__global__ __launch_bounds__(256, 2)
void k_node(const unsigned short* __restrict__ xb,   // [N,D] bf16 GEMM input
            const unsigned short* __restrict__ Wf,   // frag-layout bf16 weights
            const float* __restrict__ agg,           // [N,D] or null
            const float* __restrict__ bias,          // [D]
            const float* __restrict__ xres,          // [N,D] residual f32 or null
            const float* __restrict__ resPtr,        // scalar or null
            float* __restrict__ outF,                // [N,D] or null
            unsigned short* __restrict__ outB,       // [N,D] bf16 or null
            int N, int D, int mode)
{
    __shared__ unsigned short Alds[64 * AP];
    const int t = threadIdx.x;
    const int rBase = blockIdx.x * 64;

    {
        const int r = t >> 2, q = t & 3;
        const int row = rBase + r;
        if (row < N) {
            const unsigned short* xrow = xb + (size_t)row * D;
            #pragma unroll
            for (int c8 = 0; c8 < 8; ++c8) {
                int col = q * 64 + c8 * 8;
                *(uint4*)(&Alds[r * AP + col]) = *(const uint4*)(xrow + col);
            }
        } else {
            #pragma unroll
            for (int c8 = 0; c8 < 8; ++c8) {
                int col = q * 64 + c8 * 8;
                *(uint4*)(&Alds[r * AP + col]) = make_uint4(0, 0, 0, 0);
            }
        }
    }
    __syncthreads();

    const int w  = t >> 6;
    const int l  = t & 63;
    const int lr = l & 15;
    const int lk = (l >> 4) * 8;

    f32x4 acc[4][4] = {};

    #pragma unroll
    for (int kk = 0; kk < 8; ++kk) {
        bf16x8 a[4], b[4];
        #pragma unroll
        for (int m = 0; m < 4; ++m)
            a[m] = *(const bf16x8*)(&Alds[(16 * m + lr) * AP + kk * 32 + lk]);
        #pragma unroll
        for (int n = 0; n < 4; ++n)
            b[n] = *(const bf16x8*)(Wf + (((size_t)(kk * 16 + (w * 4 + n)) * 64 + l) * 8));
        #pragma unroll
        for (int m = 0; m < 4; ++m)
            #pragma unroll
            for (int n = 0; n < 4; ++n)
                acc[m][n] = __builtin_amdgcn_mfma_f32_16x16x32_bf16(a[m], b[n], acc[m][n], 0, 0, 0);
    }

    const int rb4 = (l >> 4) * 4;
    const float resv = resPtr ? resPtr[0] : 0.0f;
    #pragma unroll
    for (int m = 0; m < 4; ++m) {
        #pragma unroll
        for (int i = 0; i < 4; ++i) {
            int row = rBase + 16 * m + rb4 + i;
            if (row < N) {
                size_t base = (size_t)row * D + w * 64 + lr;
                #pragma unroll
                for (int n = 0; n < 4; ++n) {
                    int   c = w * 64 + lr + 16 * n;
                    float v = acc[m][n][i];
                    if (mode == 0) {
                        v += agg[base + 16 * n] + bias[c];
                        float h = xres[base + 16 * n] + resv * tanhf(v);
                        if (outF) outF[base + 16 * n] = h;
                        if (outB) outB[base + 16 * n] = f2b(h);
                    } else {
                        outF[base + 16 * n] = v + bias[c];
                    }
                }
            }
        }
    }
}

// ---------------------------------------------------------------------------

extern "C" void kernel_launch(void* const* d_in, const int* in_sizes, int n_in,
                              void* d_out, int out_size, void* d_ws, size_t ws_size,
                              hipStream_t stream)
{
    const float* emb  = (const float*)d_in[0];
    const int*   ei   = (const int*)  d_in[1];
    const int*   et   = (const int*)  d_in[2];
    const float* rel1 = (const float*)d_in[3];
    const float* Wi1  = (const float*)d_in[4];
    const float* Wo1  = (const float*)d_in[5];
    const float* Wl1  = (const float*)d_in[6];
    const float* b1   = (const float*)d_in[7];
    const float* rel2 = (const float*)d_in[8];
    const float* Wi2  = (const float*)d_in[9];
    const float* Wo2  = (const float*)d_in[10];
    const float* Wl2  = (const float*)d_in[11];
    const float* b2   = (const float*)d_in[12];
    const float* res  = (const float*)d_in[13];
    const float* muw  = (const float*)d_in[14];
    const float* mub  = (const float*)d_in[15];

    const int D = in_sizes[7];          // 256
    const int N = in_sizes[0] / D;      // 50000
    const int E = in_sizes[2];          // 320000
    const int R = in_sizes[3] / D;      // 400
    const int halfE = E / 2;            // multiple of 64
    const int* srcA = ei;
    const int* dstA = ei + E;

    // workspace carve-up (d_out doubles as the f32 'agg' scatter buffer)
    char* ws = (char*)d_ws;
    size_t off = 0;
    auto alloc = [&](size_t bytes) -> char* {
        char* p = ws + off; off += (bytes + 255) & ~(size_t)255; return p;
    };
    float*          norm = (float*)         alloc((size_t)N * 4);
    float*          h1   = (float*)         alloc((size_t)N * D * 4);
    unsigned short* xb   = (unsigned short*)alloc((size_t)N * D * 2);
    unsigned short* h1b  = (unsigned short*)alloc((size_t)N * D * 2);
    unsigned short* h2b  = (unsigned short*)alloc((size_t)N * D * 2);
    unsigned short* r1b  = (unsigned short*)alloc((size_t)R * D * 2);
    unsigned short* r2b  = (unsigned short*)alloc((size_t)R * D * 2);
    unsigned short* fWi1 = (unsigned short*)alloc((size_t)D * D * 2);
    unsigned short* fWo1 = (unsigned short*)alloc((size_t)D * D * 2);
    unsigned short* fWl1 = (unsigned short*)alloc((size_t)D * D * 2);
    unsigned short* fWi2 = (unsigned short*)alloc((size_t)D * D * 2);
    unsigned short* fWo2 = (unsigned short*)alloc((size_t)D * D * 2);
    unsigned short* fWl2 = (unsigned short*)alloc((size_t)D * D * 2);
    unsigned short* fMu  = (unsigned short*)alloc((size_t)D * D * 2);
    if (off > ws_size) return;   // insufficient scratch -> clean failure

    float* agg = (float*)d_out;  // [N,D] f32, exactly out_size

    // --- prep ---
    hipMemsetAsync(norm, 0, (size_t)N * 4, stream);
    k_deg <<<(E + 255) / 256, 256, 0, stream>>>(dstA, norm, E);
    k_norm<<<(N + 255) / 256, 256, 0, stream>>>(norm, N);

    long nd4 = (long)N * D / 4;
    k_cvt4<<<(int)((nd4 + 255) / 256), 256, 0, stream>>>(emb, xb, nd4);
    long rd4 = (long)R * D / 4;
    k_cvt4<<<(int)((rd4 + 255) / 256), 256, 0, stream>>>(rel1, r1b, rd4);
    k_cvt4<<<(int)((rd4 + 255) / 256), 256, 0, stream>>>(rel2, r2b, rd4);

    const int wb = (D * D + 255) / 256;
    k_wfrag<<<wb, 256, 0, stream>>>(Wi1, fWi1, D);
    k_wfrag<<<wb, 256, 0, stream>>>(Wo1, fWo1, D);
    k_wfrag<<<wb, 256, 0, stream>>>(Wl1, fWl1, D);
    k_wfrag<<<wb, 256, 0, stream>>>(Wi2, fWi2, D);
    k_wfrag<<<wb, 256, 0, stream>>>(Wo2, fWo2, D);
    k_wfrag<<<wb, 256, 0, stream>>>(Wl2, fWl2, D);
    k_wfrag<<<wb, 256, 0, stream>>>(muw, fMu,  D);

    const int EB = (E + 63) / 64;
    const int NB = (N + 63) / 64;

    // --- layer 1 ---
    hipMemsetAsync(agg, 0, (size_t)N * D * 4, stream);
    k_edge<<<EB, 256, 0, stream>>>(xb, r1b, srcA, dstA, et, norm, fWi1, fWo1, agg, E, halfE, D);
    k_node<<<NB, 256, 0, stream>>>(xb, fWl1, agg, b1, emb, res, h1, h1b, N, D, 0);

    // --- layer 2 ---
    hipMemsetAsync(agg, 0, (size_t)N * D * 4, stream);
    k_edge<<<EB, 256, 0, stream>>>(h1b, r2b, srcA, dstA, et, norm, fWi2, fWo2, agg, E, halfE, D);
    k_node<<<NB, 256, 0, stream>>>(h1b, fWl2, agg, b2, h1, res, nullptr, h2b, N, D, 0);

    // --- head ---
    k_node<<<NB, 256, 0, stream>>>(h2b, fMu, nullptr, mub, nullptr, nullptr, (float*)d_out, nullptr, N, D, 1);
}

// Round 2
// 408.953 us; speedup vs baseline: 1.9226x; 1.9226x over previous
//
#include <hip/hip_runtime.h>
#include <hip/hip_bf16.h>
#include <cstdint>
#include <cstddef>

// ---------------------------------------------------------------------------
// MGCN (2-layer relational GCN + linear head), CSR-gather + fused-GEMM version.
//
// Per layer:
//   s_in[v]  = norm[v] * sum_{e in first-half edges,  dst=v} x[src_e]*rel[ty_e]
//   s_out[v] = norm[v] * sum_{e in second-half edges, dst=v} x[src_e]*rel[ty_e]
//   h        = x + res * tanh( [x|s_in|s_out] @ [W_loop;W_in;W_out] + b )
// Head: out = h2 @ mu_w + mu_b
//
// No atomics in the hot path: aggregation is a per-node gather over a CSR
// built once per call.  GEMMs use v_mfma_f32_16x16x32_bf16 with weights
// repacked into B-fragment-contiguous bf16 (L2-resident).
// ---------------------------------------------------------------------------

typedef short bf16x8 __attribute__((ext_vector_type(8)));
typedef float f32x4  __attribute__((ext_vector_type(4)));

#define AP 264   // LDS A-tile pitch in bf16 elements (256 + 8 pad)

__device__ __forceinline__ float b2f(unsigned short u) {
    union { unsigned u32; float f; } c; c.u32 = ((unsigned)u) << 16; return c.f;
}
__device__ __forceinline__ unsigned short f2b(float f) {
    union { float f; unsigned u; } c; c.f = f;
    unsigned r = c.u + 0x7FFFu + ((c.u >> 16) & 1u);   // RNE
    return (unsigned short)(r >> 16);
}

// ---- CSR construction ------------------------------------------------------

__global__ void k_hist(const int* __restrict__ dst, int* __restrict__ cnt, int E) {
    int i = blockIdx.x * blockDim.x + threadIdx.x;
    if (i < E) atomicAdd(&cnt[dst[i]], 1);
}

__global__ void k_norm(const int* __restrict__ cnt, float* __restrict__ norm, int N) {
    int i = blockIdx.x * blockDim.x + threadIdx.x;
    if (i < N) norm[i] = 1.0f / fmaxf((float)cnt[i], 1.0f);
}

// exclusive scan, stage 1: per-256-block scan + block totals
__global__ void k_scan1(const int* __restrict__ cnt, int* __restrict__ part,
                        int* __restrict__ bsum, int N) {
    __shared__ int s[256];
    int i = blockIdx.x * 256 + threadIdx.x;
    int v = (i < N) ? cnt[i] : 0;
    s[threadIdx.x] = v; __syncthreads();
    #pragma unroll
    for (int o = 1; o < 256; o <<= 1) {
        int t = (threadIdx.x >= o) ? s[threadIdx.x - o] : 0;
        __syncthreads();
        s[threadIdx.x] += t;
        __syncthreads();
    }
    if (i < N) part[i] = s[threadIdx.x] - v;            // exclusive
    if (threadIdx.x == 255) bsum[blockIdx.x] = s[255];  // block total
}

// stage 2: single-block exclusive scan of block totals (nb <= 256)
__global__ void k_scan2(int* __restrict__ bsum, int nb) {
    __shared__ int s[256];
    int v = (threadIdx.x < nb) ? bsum[threadIdx.x] : 0;
    s[threadIdx.x] = v; __syncthreads();
    #pragma unroll
    for (int o = 1; o < 256; o <<= 1) {
        int t = (threadIdx.x >= o) ? s[threadIdx.x - o] : 0;
        __syncthreads();
        s[threadIdx.x] += t;
        __syncthreads();
    }
    if (threadIdx.x < nb) bsum[threadIdx.x] = s[threadIdx.x] - v;
}

// stage 3: combine -> rowptr, cursor
__global__ void k_scan3(const int* __restrict__ part, const int* __restrict__ bsum,
                        int* __restrict__ rowptr, int* __restrict__ cursor, int N, int E) {
    int i = blockIdx.x * 256 + threadIdx.x;
    if (i < N) {
        int r = part[i] + bsum[blockIdx.x];
        rowptr[i] = r; cursor[i] = r;
    }
    if (i == 0) rowptr[N] = E;
}

// scatter edges into CSR slots; record packs src(16b) | etype(15b) | dir(1b)
__global__ void k_scatter(const int* __restrict__ src, const int* __restrict__ dst,
                          const int* __restrict__ et, int* __restrict__ cursor,
                          unsigned* __restrict__ erec, int E, int halfE) {
    int e = blockIdx.x * blockDim.x + threadIdx.x;
    if (e < E) {
        int d = dst[e];
        int pos = atomicAdd(&cursor[d], 1);
        unsigned rec = (unsigned)src[e] | ((unsigned)et[e] << 16)
                     | ((e >= halfE) ? 0x80000000u : 0u);
        erec[pos] = rec;
    }
}

// ---- dtype prep ------------------------------------------------------------

__global__ void k_cvt4(const float* __restrict__ in, unsigned short* __restrict__ out, long n4) {
    long i = (long)blockIdx.x * blockDim.x + threadIdx.x;
    if (i < n4) {
        float4 v = ((const float4*)in)[i];
        ushort4 o;
        o.x = f2b(v.x); o.y = f2b(v.y); o.z = f2b(v.z); o.w = f2b(v.w);
        ((ushort4*)out)[i] = o;
    }
}

// Repack W[D][D] (row-major f32, k-major) into MFMA-B fragment layout bf16:
// out[((kk*16+nn)*64 + l)*8 + j] = W[kk*32 + (l>>4)*8 + j][nn*16 + (l&15)]
__global__ void k_wfrag(const float* __restrict__ W, unsigned short* __restrict__ out, int D) {
    int o = blockIdx.x * blockDim.x + threadIdx.x;
    if (o < D * D) {
        int j  = o & 7;
        int l  = (o >> 3) & 63;
        int nn = (o >> 9) & 15;
        int kk = o >> 13;
        int k = kk * 32 + (l >> 4) * 8 + j;
        int n = nn * 16 + (l & 15);
        out[o] = f2b(W[(size_t)k * D + n]);
    }
}

// ---- CSR gather aggregation (no atomics) ----------------------------------
// 1 wave per node; lane l owns cols l*4 .. l*4+3.

__global__ __launch_bounds__(256)
void k_agg(const unsigned short* __restrict__ xb, const unsigned short* __restrict__ relb,
           const int* __restrict__ rowptr, const unsigned* __restrict__ erec,
           const float* __restrict__ norm,
           unsigned short* __restrict__ sIn, unsigned short* __restrict__ sOut,
           int N, int D)
{
    const int w = threadIdx.x >> 6, l = threadIdx.x & 63;
    const int v = blockIdx.x * 4 + w;
    if (v >= N) return;
    const int rs = rowptr[v], re = rowptr[v + 1];

    float ai0 = 0, ai1 = 0, ai2 = 0, ai3 = 0;
    float ao0 = 0, ao1 = 0, ao2 = 0, ao3 = 0;

    unsigned rec = (rs < re) ? erec[rs] : 0u;
    for (int i = rs; i < re; ++i) {
        unsigned cur = rec;
        if (i + 1 < re) rec = erec[i + 1];           // prefetch next record
        int s  = cur & 0xffff;
        int ty = (cur >> 16) & 0x7fff;
        ushort4 xv = *(const ushort4*)(xb   + (size_t)s  * D + l * 4);
        ushort4 rv = *(const ushort4*)(relb + (size_t)ty * D + l * 4);
        float p0 = b2f(xv.x) * b2f(rv.x);
        float p1 = b2f(xv.y) * b2f(rv.y);
        float p2 = b2f(xv.z) * b2f(rv.z);
        float p3 = b2f(xv.w) * b2f(rv.w);
        if (cur >> 31) { ao0 += p0; ao1 += p1; ao2 += p2; ao3 += p3; }
        else           { ai0 += p0; ai1 += p1; ai2 += p2; ai3 += p3; }
    }

    float nm = norm[v];
    ushort4 oi, oo;
    oi.x = f2b(ai0 * nm); oi.y = f2b(ai1 * nm); oi.z = f2b(ai2 * nm); oi.w = f2b(ai3 * nm);
    oo.x = f2b(ao0 * nm); oo.y = f2b(ao1 * nm); oo.z = f2b(ao2 * nm); oo.w = f2b(ao3 * nm);
    *(ushort4*)(sIn  + (size_t)v * D + l * 4) = oi;
    *(ushort4*)(sOut + (size_t)v * D + l * 4) = oo;
}

// ---- fused node GEMM: acc = sum_p  A_p @ W_p  -----------------------------
// mode 0: h = xres + res * tanh(acc + bias); write outF (f32) / outB (bf16)
// mode 1: outF = acc + bias

__global__ __launch_bounds__(256, 2)
void k_node3(const unsigned short* __restrict__ a0,
             const unsigned short* __restrict__ a1,
             const unsigned short* __restrict__ a2,
             const unsigned short* __restrict__ Wf,   // frag layout, nsrc*D*D
             const float* __restrict__ bias,
             const float* __restrict__ xres,          // residual f32 or null
             const float* __restrict__ resPtr,        // scalar or null
             float* __restrict__ outF,
             unsigned short* __restrict__ outB,
             int N, int D, int nsrc, int mode)
{
    __shared__ unsigned short Alds[64 * AP];
    const int t = threadIdx.x;
    const int rBase = blockIdx.x * 64;

    const int w  = t >> 6;
    const int l  = t & 63;
    const int lr = l & 15;
    const int lk = (l >> 4) * 8;

    f32x4 acc[4][4] = {};

    for (int p = 0; p < nsrc; ++p) {
        const unsigned short* __restrict__ ap = (p == 0) ? a0 : ((p == 1) ? a1 : a2);

        // stage 64 x 256 bf16 tile
        {
            const int r = t >> 2, q = t & 3;
            const int row = rBase + r;
            if (row < N) {
                const unsigned short* xrow = ap + (size_t)row * D;
                #pragma unroll
                for (int c8 = 0; c8 < 8; ++c8) {
                    int col = q * 64 + c8 * 8;
                    *(uint4*)(&Alds[r * AP + col]) = *(const uint4*)(xrow + col);
                }
            } else {
                #pragma unroll
                for (int c8 = 0; c8 < 8; ++c8) {
                    int col = q * 64 + c8 * 8;
                    *(uint4*)(&Alds[r * AP + col]) = make_uint4(0, 0, 0, 0);
                }
            }
        }
        __syncthreads();

        const unsigned short* __restrict__ Wp = Wf + (size_t)p * D * D;
        #pragma unroll
        for (int kk = 0; kk < 8; ++kk) {
            bf16x8 a[4], b[4];
            #pragma unroll
            for (int m = 0; m < 4; ++m)
                a[m] = *(const bf16x8*)(&Alds[(16 * m + lr) * AP + kk * 32 + lk]);
            #pragma unroll
            for (int n = 0; n < 4; ++n)
                b[n] = *(const bf16x8*)(Wp + (((size_t)(kk * 16 + (w * 4 + n)) * 64 + l) * 8));
            #pragma unroll
            for (int m = 0; m < 4; ++m)
                #pragma unroll
                for (int n = 0; n < 4; ++n)
                    acc[m][n] = __builtin_amdgcn_mfma_f32_16x16x32_bf16(a[m], b[n], acc[m][n], 0, 0, 0);
        }
        __syncthreads();
    }

    const int rb4 = (l >> 4) * 4;
    const float resv = resPtr ? resPtr[0] : 0.0f;
    #pragma unroll
    for (int m = 0; m < 4; ++m) {
        #pragma unroll
        for (int i = 0; i < 4; ++i) {
            int row = rBase + 16 * m + rb4 + i;
            if (row < N) {
                size_t base = (size_t)row * D + w * 64 + lr;
                #pragma unroll
                for (int n = 0; n < 4; ++n) {
                    int   c = w * 64 + lr + 16 * n;
                    float v = acc[m][n][i] + bias[c];
                    if (mode == 0) {
                        float h = xres[base + 16 * n] + resv * tanhf(v);
                        if (outF) outF[base + 16 * n] = h;
                        if (outB) outB[base + 16 * n] = f2b(h);
                    } else {
                        outF[base + 16 * n] = v;
                    }
                }
            }
        }
    }
}

// ---------------------------------------------------------------------------

extern "C" void kernel_launch(void* const* d_in, const int* in_sizes, int n_in,
                              void* d_out, int out_size, void* d_ws, size_t ws_size,
                              hipStream_t stream)
{
    const float* emb  = (const float*)d_in[0];
    const int*   ei   = (const int*)  d_in[1];
    const int*   et   = (const int*)  d_in[2];
    const float* rel1 = (const float*)d_in[3];
    const float* Wi1  = (const float*)d_in[4];
    const float* Wo1  = (const float*)d_in[5];
    const float* Wl1  = (const float*)d_in[6];
    const float* b1   = (const float*)d_in[7];
    const float* rel2 = (const float*)d_in[8];
    const float* Wi2  = (const float*)d_in[9];
    const float* Wo2  = (const float*)d_in[10];
    const float* Wl2  = (const float*)d_in[11];
    const float* b2   = (const float*)d_in[12];
    const float* res  = (const float*)d_in[13];
    const float* muw  = (const float*)d_in[14];
    const float* mub  = (const float*)d_in[15];

    const int D = in_sizes[7];          // 256
    const int N = in_sizes[0] / D;      // 50000
    const int E = in_sizes[2];          // 320000
    const int R = in_sizes[3] / D;      // 400
    const int halfE = E / 2;
    const int* srcA = ei;
    const int* dstA = ei + E;
    const size_t DD = (size_t)D * D;

    // workspace carve-up
    char* ws = (char*)d_ws;
    size_t off = 0;
    auto alloc = [&](size_t bytes) -> char* {
        char* p = ws + off; off += (bytes + 255) & ~(size_t)255; return p;
    };
    const int nb1 = (N + 255) / 256;    // scan blocks (196 <= 256)

    float*          norm   = (float*)         alloc((size_t)N * 4);
    int*            cnt    = (int*)            alloc((size_t)N * 4);
    int*            rowptr = (int*)            alloc((size_t)(N + 1) * 4);
    int*            cursor = (int*)            alloc((size_t)N * 4);
    int*            part   = (int*)            alloc((size_t)N * 4);
    int*            bsum   = (int*)            alloc(1024);
    unsigned*       erec   = (unsigned*)       alloc((size_t)E * 4);
    unsigned short* xb     = (unsigned short*) alloc((size_t)N * D * 2);
    unsigned short* h1b    = (unsigned short*) alloc((size_t)N * D * 2);
    unsigned short* sIn    = (unsigned short*) alloc((size_t)N * D * 2);
    unsigned short* sOut   = (unsigned short*) alloc((size_t)N * D * 2);
    unsigned short* r1b    = (unsigned short*) alloc((size_t)R * D * 2);
    unsigned short* r2b    = (unsigned short*) alloc((size_t)R * D * 2);
    unsigned short* fW1    = (unsigned short*) alloc(3 * DD * 2);
    unsigned short* fW2    = (unsigned short*) alloc(3 * DD * 2);
    unsigned short* fMu    = (unsigned short*) alloc(DD * 2);
    if (off > ws_size) return;

    float*          h1  = (float*)d_out;   // f32 residual buffer, overwritten by head
    unsigned short* h2b = xb;              // xb dead after layer-1 GEMM

    // --- CSR + norm ---
    hipMemsetAsync(cnt, 0, (size_t)N * 4, stream);
    k_hist   <<<(E + 255) / 256, 256, 0, stream>>>(dstA, cnt, E);
    k_norm   <<<nb1, 256, 0, stream>>>(cnt, norm, N);
    k_scan1  <<<nb1, 256, 0, stream>>>(cnt, part, bsum, N);
    k_scan2  <<<1,   256, 0, stream>>>(bsum, nb1);
    k_scan3  <<<nb1, 256, 0, stream>>>(part, bsum, rowptr, cursor, N, E);
    k_scatter<<<(E + 255) / 256, 256, 0, stream>>>(srcA, dstA, et, cursor, erec, E, halfE);

    // --- dtype prep ---
    long nd4 = (long)N * D / 4;
    k_cvt4<<<(int)((nd4 + 255) / 256), 256, 0, stream>>>(emb, xb, nd4);
    long rd4 = (long)R * D / 4;
    k_cvt4<<<(int)((rd4 + 255) / 256), 256, 0, stream>>>(rel1, r1b, rd4);
    k_cvt4<<<(int)((rd4 + 255) / 256), 256, 0, stream>>>(rel2, r2b, rd4);

    const int wb = (int)((DD + 255) / 256);
    k_wfrag<<<wb, 256, 0, stream>>>(Wl1, fW1,          D);
    k_wfrag<<<wb, 256, 0, stream>>>(Wi1, fW1 + DD,     D);
    k_wfrag<<<wb, 256, 0, stream>>>(Wo1, fW1 + 2 * DD, D);
    k_wfrag<<<wb, 256, 0, stream>>>(Wl2, fW2,          D);
    k_wfrag<<<wb, 256, 0, stream>>>(Wi2, fW2 + DD,     D);
    k_wfrag<<<wb, 256, 0, stream>>>(Wo2, fW2 + 2 * DD, D);
    k_wfrag<<<wb, 256, 0, stream>>>(muw, fMu,          D);

    const int AB = (N + 3) / 4;     // k_agg blocks (4 nodes/block)
    const int NB = (N + 63) / 64;   // GEMM blocks

    // --- layer 1 ---
    k_agg  <<<AB, 256, 0, stream>>>(xb, r1b, rowptr, erec, norm, sIn, sOut, N, D);
    k_node3<<<NB, 256, 0, stream>>>(xb, sIn, sOut, fW1, b1, emb, res, h1, h1b, N, D, 3, 0);

    // --- layer 2 ---
    k_agg  <<<AB, 256, 0, stream>>>(h1b, r2b, rowptr, erec, norm, sIn, sOut, N, D);
    k_node3<<<NB, 256, 0, stream>>>(h1b, sIn, sOut, fW2, b2, h1, res, nullptr, h2b, N, D, 3, 0);

    // --- head ---
    k_node3<<<NB, 256, 0, stream>>>(h2b, nullptr, nullptr, fMu, mub, nullptr, nullptr,
                                    (float*)d_out, nullptr, N, D, 1, 1);
}

// Round 3
// 298.039 us; speedup vs baseline: 2.6380x; 1.3721x over previous
//
#include <hip/hip_runtime.h>
#include <hip/hip_bf16.h>
#include <cstdint>
#include <cstddef>

// ---------------------------------------------------------------------------
// MGCN (2-layer relational GCN + linear head), CSR-gather + fused-GEMM version.
//
// Per layer:
//   s_in[v]  = norm[v] * sum_{first-half edges,  dst=v} x[src]*rel[ty]
//   s_out[v] = norm[v] * sum_{second-half edges, dst=v} x[src]*rel[ty]
//   h        = x + res * tanh( [x|s_in|s_out] @ [W_loop;W_in;W_out] + b )
// Head: out = h2 @ mu_w + mu_b
//
// GEMM: K=768 in 12 steps of BK=64 over one 8KB XOR-swizzled LDS tile,
// reg-staged with issue-early/write-late prefetch, 4 blocks/CU.
// ---------------------------------------------------------------------------

typedef short bf16x8 __attribute__((ext_vector_type(8)));
typedef float f32x4  __attribute__((ext_vector_type(4)));

__device__ __forceinline__ float b2f(unsigned short u) {
    union { unsigned u32; float f; } c; c.u32 = ((unsigned)u) << 16; return c.f;
}
__device__ __forceinline__ unsigned short f2b(float f) {
    union { float f; unsigned u; } c; c.f = f;
    unsigned r = c.u + 0x7FFFu + ((c.u >> 16) & 1u);   // RNE
    return (unsigned short)(r >> 16);
}

// ---- CSR construction ------------------------------------------------------

__global__ void k_hist(const int* __restrict__ dst, int* __restrict__ cnt, int E) {
    int i = blockIdx.x * blockDim.x + threadIdx.x;
    if (i < E) atomicAdd(&cnt[dst[i]], 1);
}

__global__ void k_norm(const int* __restrict__ cnt, float* __restrict__ norm, int N) {
    int i = blockIdx.x * blockDim.x + threadIdx.x;
    if (i < N) norm[i] = 1.0f / fmaxf((float)cnt[i], 1.0f);
}

__global__ void k_scan1(const int* __restrict__ cnt, int* __restrict__ part,
                        int* __restrict__ bsum, int N) {
    __shared__ int s[256];
    int i = blockIdx.x * 256 + threadIdx.x;
    int v = (i < N) ? cnt[i] : 0;
    s[threadIdx.x] = v; __syncthreads();
    #pragma unroll
    for (int o = 1; o < 256; o <<= 1) {
        int t = (threadIdx.x >= o) ? s[threadIdx.x - o] : 0;
        __syncthreads();
        s[threadIdx.x] += t;
        __syncthreads();
    }
    if (i < N) part[i] = s[threadIdx.x] - v;
    if (threadIdx.x == 255) bsum[blockIdx.x] = s[255];
}

__global__ void k_scan2(int* __restrict__ bsum, int nb) {
    __shared__ int s[256];
    int v = (threadIdx.x < nb) ? bsum[threadIdx.x] : 0;
    s[threadIdx.x] = v; __syncthreads();
    #pragma unroll
    for (int o = 1; o < 256; o <<= 1) {
        int t = (threadIdx.x >= o) ? s[threadIdx.x - o] : 0;
        __syncthreads();
        s[threadIdx.x] += t;
        __syncthreads();
    }
    if (threadIdx.x < nb) bsum[threadIdx.x] = s[threadIdx.x] - v;
}

__global__ void k_scan3(const int* __restrict__ part, const int* __restrict__ bsum,
                        int* __restrict__ rowptr, int* __restrict__ cursor, int N, int E) {
    int i = blockIdx.x * 256 + threadIdx.x;
    if (i < N) {
        int r = part[i] + bsum[blockIdx.x];
        rowptr[i] = r; cursor[i] = r;
    }
    if (i == 0) rowptr[N] = E;
}

__global__ void k_scatter(const int* __restrict__ src, const int* __restrict__ dst,
                          const int* __restrict__ et, int* __restrict__ cursor,
                          unsigned* __restrict__ erec, int E, int halfE) {
    int e = blockIdx.x * blockDim.x + threadIdx.x;
    if (e < E) {
        int d = dst[e];
        int pos = atomicAdd(&cursor[d], 1);
        unsigned rec = (unsigned)src[e] | ((unsigned)et[e] << 16)
                     | ((e >= halfE) ? 0x80000000u : 0u);
        erec[pos] = rec;
    }
}

// ---- dtype prep ------------------------------------------------------------

__global__ void k_cvt4(const float* __restrict__ in, unsigned short* __restrict__ out, long n4) {
    long i = (long)blockIdx.x * blockDim.x + threadIdx.x;
    if (i < n4) {
        float4 v = ((const float4*)in)[i];
        ushort4 o;
        o.x = f2b(v.x); o.y = f2b(v.y); o.z = f2b(v.z); o.w = f2b(v.w);
        ((ushort4*)out)[i] = o;
    }
}

// Repack W[D][D] (row-major f32, k-major) into MFMA-B fragment layout bf16:
// out[((kg*16+nn)*64 + l)*8 + j] = W[kg*32 + (l>>4)*8 + j][nn*16 + (l&15)]
__global__ void k_wfrag(const float* __restrict__ W, unsigned short* __restrict__ out, int D) {
    int o = blockIdx.x * blockDim.x + threadIdx.x;
    if (o < D * D) {
        int j  = o & 7;
        int l  = (o >> 3) & 63;
        int nn = (o >> 9) & 15;
        int kg = o >> 13;
        int k = kg * 32 + (l >> 4) * 8 + j;
        int n = nn * 16 + (l & 15);
        out[o] = f2b(W[(size_t)k * D + n]);
    }
}

// ---- CSR gather aggregation (no atomics) ----------------------------------

__global__ __launch_bounds__(256)
void k_agg(const unsigned short* __restrict__ xb, const unsigned short* __restrict__ relb,
           const int* __restrict__ rowptr, const unsigned* __restrict__ erec,
           const float* __restrict__ norm,
           unsigned short* __restrict__ sIn, unsigned short* __restrict__ sOut,
           int N, int D)
{
    const int w = threadIdx.x >> 6, l = threadIdx.x & 63;
    const int v = blockIdx.x * 4 + w;
    if (v >= N) return;
    const int rs = rowptr[v], re = rowptr[v + 1];

    float ai0 = 0, ai1 = 0, ai2 = 0, ai3 = 0;
    float ao0 = 0, ao1 = 0, ao2 = 0, ao3 = 0;

    unsigned rec = (rs < re) ? erec[rs] : 0u;
    for (int i = rs; i < re; ++i) {
        unsigned cur = rec;
        if (i + 1 < re) rec = erec[i + 1];
        int s  = cur & 0xffff;
        int ty = (cur >> 16) & 0x7fff;
        ushort4 xv = *(const ushort4*)(xb   + (size_t)s  * D + l * 4);
        ushort4 rv = *(const ushort4*)(relb + (size_t)ty * D + l * 4);
        float p0 = b2f(xv.x) * b2f(rv.x);
        float p1 = b2f(xv.y) * b2f(rv.y);
        float p2 = b2f(xv.z) * b2f(rv.z);
        float p3 = b2f(xv.w) * b2f(rv.w);
        if (cur >> 31) { ao0 += p0; ao1 += p1; ao2 += p2; ao3 += p3; }
        else           { ai0 += p0; ai1 += p1; ai2 += p2; ai3 += p3; }
    }

    float nm = norm[v];
    ushort4 oi, oo;
    oi.x = f2b(ai0 * nm); oi.y = f2b(ai1 * nm); oi.z = f2b(ai2 * nm); oi.w = f2b(ai3 * nm);
    oo.x = f2b(ao0 * nm); oo.y = f2b(ao1 * nm); oo.z = f2b(ao2 * nm); oo.w = f2b(ao3 * nm);
    *(ushort4*)(sIn  + (size_t)v * D + l * 4) = oi;
    *(ushort4*)(sOut + (size_t)v * D + l * 4) = oo;
}

// ---- fused node GEMM: acc = sum_p A_p @ W_p, K = nsrc*256 -----------------
// outB != null (layer):  h = bf16(a0[row]) + res * tanh(acc + bias) -> outB
// outB == null (head) :  outF = acc + bias
//
// BK=64 steps over one 64x64 bf16 LDS tile, XOR-swizzled (chunk ^= row&7),
// reg-staged with prefetch-into-registers one step ahead.

__global__ __launch_bounds__(256, 4)
void k_gemm(const unsigned short* __restrict__ a0,
            const unsigned short* __restrict__ a1,
            const unsigned short* __restrict__ a2,
            const unsigned short* __restrict__ Wf,   // frag layout, nsrc*D*D
            const float* __restrict__ bias,
            const float* __restrict__ resPtr,
            float* __restrict__ outF,
            unsigned short* __restrict__ outB,
            int N, int D, int nsrc)
{
    __shared__ unsigned short At[64 * 64];    // 8 KB
    const int t = threadIdx.x;
    const int rBase = blockIdx.x * 64;
    const int NT = nsrc * 4;

    const int w  = t >> 6;
    const int l  = t & 63;
    const int lr = l & 15;
    const int lq = l >> 4;

    // staging geometry: thread t covers chunk (row r, chunk c) for parts i=0,1
    const int rS0 = t >> 3;                 // 0..31
    const int rS1 = rS0 + 32;               // 32..63
    const int cS  = t & 7;                  // 16B chunk in row
    const int wo0 = rS0 * 64 + ((cS ^ (rS0 & 7)) * 8);   // swizzled LDS ushort idx
    const int wo1 = rS1 * 64 + ((cS ^ (rS1 & 7)) * 8);
    const size_t g0 = (size_t)min(rBase + rS0, N - 1) * D + cS * 8;
    const size_t g1 = (size_t)min(rBase + rS1, N - 1) * D + cS * 8;

    f32x4 acc[4][4] = {};
    uint4 R0, R1;

    R0 = *(const uint4*)(a0 + g0);          // prologue: step 0
    R1 = *(const uint4*)(a0 + g1);

    for (int s = 0; s < NT; ++s) {
        *(uint4*)(&At[wo0]) = R0;
        *(uint4*)(&At[wo1]) = R1;
        __syncthreads();                     // (A) tile visible

        if (s + 1 < NT) {                    // issue next step's loads now;
            int p = (s + 1) >> 2;            // they drain at barrier (B),
            int cb = (s + 1) & 3;            // hidden under the MFMA phase
            const unsigned short* ap = (p == 0) ? a0 : ((p == 1) ? a1 : a2);
            R0 = *(const uint4*)(ap + g0 + cb * 64);
            R1 = *(const uint4*)(ap + g1 + cb * 64);
        }

        {
            const int p = s >> 2, cb = s & 3;
            const unsigned short* __restrict__ Wp = Wf + (size_t)p * D * D;
            #pragma unroll
            for (int kk = 0; kk < 2; ++kk) {
                const int kg = cb * 2 + kk;
                bf16x8 a[4], b[4];
                #pragma unroll
                for (int m = 0; m < 4; ++m) {
                    int rm = 16 * m + lr;
                    int ch = (kk * 4 + lq) ^ (rm & 7);
                    a[m] = *(const bf16x8*)(&At[rm * 64 + ch * 8]);
                }
                #pragma unroll
                for (int n = 0; n < 4; ++n)
                    b[n] = *(const bf16x8*)(Wf + (size_t)p * D * D
                             + (((size_t)(kg * 16 + (w * 4 + n)) * 64 + l) * 8));
                #pragma unroll
                for (int m = 0; m < 4; ++m)
                    #pragma unroll
                    for (int n = 0; n < 4; ++n)
                        acc[m][n] = __builtin_amdgcn_mfma_f32_16x16x32_bf16(a[m], b[n], acc[m][n], 0, 0, 0);
            }
            (void)Wp;
        }
        __syncthreads();                     // (B) all waves done reading tile
    }

    const int rb4 = lq * 4;
    const float resv = resPtr ? resPtr[0] : 0.0f;
    #pragma unroll
    for (int m = 0; m < 4; ++m) {
        #pragma unroll
        for (int i = 0; i < 4; ++i) {
            int row = rBase + 16 * m + rb4 + i;
            if (row < N) {
                size_t base = (size_t)row * D + w * 64 + lr;
                #pragma unroll
                for (int n = 0; n < 4; ++n) {
                    int   c = w * 64 + lr + 16 * n;
                    float v = acc[m][n][i] + bias[c];
                    if (outB) {
                        float h = b2f(a0[base + 16 * n]) + resv * tanhf(v);
                        outB[base + 16 * n] = f2b(h);
                    } else {
                        outF[base + 16 * n] = v;
                    }
                }
            }
        }
    }
}

// ---------------------------------------------------------------------------

extern "C" void kernel_launch(void* const* d_in, const int* in_sizes, int n_in,
                              void* d_out, int out_size, void* d_ws, size_t ws_size,
                              hipStream_t stream)
{
    const float* emb  = (const float*)d_in[0];
    const int*   ei   = (const int*)  d_in[1];
    const int*   et   = (const int*)  d_in[2];
    const float* rel1 = (const float*)d_in[3];
    const float* Wi1  = (const float*)d_in[4];
    const float* Wo1  = (const float*)d_in[5];
    const float* Wl1  = (const float*)d_in[6];
    const float* b1   = (const float*)d_in[7];
    const float* rel2 = (const float*)d_in[8];
    const float* Wi2  = (const float*)d_in[9];
    const float* Wo2  = (const float*)d_in[10];
    const float* Wl2  = (const float*)d_in[11];
    const float* b2   = (const float*)d_in[12];
    const float* res  = (const float*)d_in[13];
    const float* muw  = (const float*)d_in[14];
    const float* mub  = (const float*)d_in[15];

    const int D = in_sizes[7];          // 256
    const int N = in_sizes[0] / D;      // 50000
    const int E = in_sizes[2];          // 320000
    const int R = in_sizes[3] / D;      // 400
    const int halfE = E / 2;
    const int* srcA = ei;
    const int* dstA = ei + E;
    const size_t DD = (size_t)D * D;

    char* ws = (char*)d_ws;
    size_t off = 0;
    auto alloc = [&](size_t bytes) -> char* {
        char* p = ws + off; off += (bytes + 255) & ~(size_t)255; return p;
    };
    const int nb1 = (N + 255) / 256;

    float*          norm   = (float*)          alloc((size_t)N * 4);
    int*            cnt    = (int*)            alloc((size_t)N * 4);
    int*            rowptr = (int*)            alloc((size_t)(N + 1) * 4);
    int*            cursor = (int*)            alloc((size_t)N * 4);
    int*            part   = (int*)            alloc((size_t)N * 4);
    int*            bsum   = (int*)            alloc(1024);
    unsigned*       erec   = (unsigned*)       alloc((size_t)E * 4);
    unsigned short* xb     = (unsigned short*) alloc((size_t)N * D * 2);
    unsigned short* h1b    = (unsigned short*) alloc((size_t)N * D * 2);
    unsigned short* sIn    = (unsigned short*) alloc((size_t)N * D * 2);
    unsigned short* sOut   = (unsigned short*) alloc((size_t)N * D * 2);
    unsigned short* r1b    = (unsigned short*) alloc((size_t)R * D * 2);
    unsigned short* r2b    = (unsigned short*) alloc((size_t)R * D * 2);
    unsigned short* fW1    = (unsigned short*) alloc(3 * DD * 2);
    unsigned short* fW2    = (unsigned short*) alloc(3 * DD * 2);
    unsigned short* fMu    = (unsigned short*) alloc(DD * 2);
    if (off > ws_size) return;

    unsigned short* h2b = xb;              // xb dead after layer-1 GEMM

    // --- CSR + norm ---
    hipMemsetAsync(cnt, 0, (size_t)N * 4, stream);
    k_hist   <<<(E + 255) / 256, 256, 0, stream>>>(dstA, cnt, E);
    k_norm   <<<nb1, 256, 0, stream>>>(cnt, norm, N);
    k_scan1  <<<nb1, 256, 0, stream>>>(cnt, part, bsum, N);
    k_scan2  <<<1,   256, 0, stream>>>(bsum, nb1);
    k_scan3  <<<nb1, 256, 0, stream>>>(part, bsum, rowptr, cursor, N, E);
    k_scatter<<<(E + 255) / 256, 256, 0, stream>>>(srcA, dstA, et, cursor, erec, E, halfE);

    // --- dtype prep ---
    long nd4 = (long)N * D / 4;
    k_cvt4<<<(int)((nd4 + 255) / 256), 256, 0, stream>>>(emb, xb, nd4);
    long rd4 = (long)R * D / 4;
    k_cvt4<<<(int)((rd4 + 255) / 256), 256, 0, stream>>>(rel1, r1b, rd4);
    k_cvt4<<<(int)((rd4 + 255) / 256), 256, 0, stream>>>(rel2, r2b, rd4);

    const int wb = (int)((DD + 255) / 256);
    k_wfrag<<<wb, 256, 0, stream>>>(Wl1, fW1,          D);
    k_wfrag<<<wb, 256, 0, stream>>>(Wi1, fW1 + DD,     D);
    k_wfrag<<<wb, 256, 0, stream>>>(Wo1, fW1 + 2 * DD, D);
    k_wfrag<<<wb, 256, 0, stream>>>(Wl2, fW2,          D);
    k_wfrag<<<wb, 256, 0, stream>>>(Wi2, fW2 + DD,     D);
    k_wfrag<<<wb, 256, 0, stream>>>(Wo2, fW2 + 2 * DD, D);
    k_wfrag<<<wb, 256, 0, stream>>>(muw, fMu,          D);

    const int AB = (N + 3) / 4;
    const int NB = (N + 63) / 64;

    // --- layer 1 ---
    k_agg <<<AB, 256, 0, stream>>>(xb, r1b, rowptr, erec, norm, sIn, sOut, N, D);
    k_gemm<<<NB, 256, 0, stream>>>(xb, sIn, sOut, fW1, b1, res, nullptr, h1b, N, D, 3);

    // --- layer 2 ---
    k_agg <<<AB, 256, 0, stream>>>(h1b, r2b, rowptr, erec, norm, sIn, sOut, N, D);
    k_gemm<<<NB, 256, 0, stream>>>(h1b, sIn, sOut, fW2, b2, res, nullptr, h2b, N, D, 3);

    // --- head ---
    k_gemm<<<NB, 256, 0, stream>>>(h2b, nullptr, nullptr, fMu, mub, nullptr,
                                   (float*)d_out, nullptr, N, D, 1);
}

// Round 4
// 243.634 us; speedup vs baseline: 3.2271x; 1.2233x over previous
//
#include <hip/hip_runtime.h>
#include <hip/hip_bf16.h>
#include <cstdint>
#include <cstddef>

// ---------------------------------------------------------------------------
// MGCN (2-layer relational GCN + linear head).
//
//   s_in[v]  = norm[v] * sum_{first-half edges,  dst=v} x[src]*rel[ty]
//   s_out[v] = norm[v] * sum_{second-half edges, dst=v} x[src]*rel[ty]
//   h        = x + res * tanh( [x|s_in|s_out] @ [W_loop;W_in;W_out] + b )
//   out      = h2 @ mu_w + mu_b        (fused into the layer-2 kernel)
//
// GEMM: 64-row tiles, K=768 in 12 BK=64 steps, 2-deep reg-staged pipeline
// with ONE raw s_barrier per step (no vmcnt drain — loads fly across
// barriers; compiler's dependency waits provide the counted vmcnt).
// ---------------------------------------------------------------------------

typedef short bf16x8 __attribute__((ext_vector_type(8)));
typedef float f32x4  __attribute__((ext_vector_type(4)));

__device__ __forceinline__ float b2f(unsigned short u) {
    union { unsigned u32; float f; } c; c.u32 = ((unsigned)u) << 16; return c.f;
}
__device__ __forceinline__ unsigned short f2b(float f) {
    union { float f; unsigned u; } c; c.f = f;
    unsigned r = c.u + 0x7FFFu + ((c.u >> 16) & 1u);   // RNE
    return (unsigned short)(r >> 16);
}
__device__ __forceinline__ float ftanh(float x) {
    // tanh(x) = 1 - 2/(e^{2x}+1); exact at +-inf, ~1e-6 abs err
    float e = __expf(2.0f * x);
    return 1.0f - __fdividef(2.0f, e + 1.0f);
}

// ---- CSR construction ------------------------------------------------------

__global__ void k_hist(const int* __restrict__ dst, int* __restrict__ cnt, int E) {
    int i = blockIdx.x * blockDim.x + threadIdx.x;
    if (i < E) atomicAdd(&cnt[dst[i]], 1);
}

__global__ void k_norm(const int* __restrict__ cnt, float* __restrict__ norm, int N) {
    int i = blockIdx.x * blockDim.x + threadIdx.x;
    if (i < N) norm[i] = 1.0f / fmaxf((float)cnt[i], 1.0f);
}

__global__ void k_scan1(const int* __restrict__ cnt, int* __restrict__ part,
                        int* __restrict__ bsum, int N) {
    __shared__ int s[256];
    int i = blockIdx.x * 256 + threadIdx.x;
    int v = (i < N) ? cnt[i] : 0;
    s[threadIdx.x] = v; __syncthreads();
    #pragma unroll
    for (int o = 1; o < 256; o <<= 1) {
        int t = (threadIdx.x >= o) ? s[threadIdx.x - o] : 0;
        __syncthreads();
        s[threadIdx.x] += t;
        __syncthreads();
    }
    if (i < N) part[i] = s[threadIdx.x] - v;
    if (threadIdx.x == 255) bsum[blockIdx.x] = s[255];
}

__global__ void k_scan2(int* __restrict__ bsum, int nb) {
    __shared__ int s[256];
    int v = (threadIdx.x < nb) ? bsum[threadIdx.x] : 0;
    s[threadIdx.x] = v; __syncthreads();
    #pragma unroll
    for (int o = 1; o < 256; o <<= 1) {
        int t = (threadIdx.x >= o) ? s[threadIdx.x - o] : 0;
        __syncthreads();
        s[threadIdx.x] += t;
        __syncthreads();
    }
    if (threadIdx.x < nb) bsum[threadIdx.x] = s[threadIdx.x] - v;
}

__global__ void k_scan3(const int* __restrict__ part, const int* __restrict__ bsum,
                        int* __restrict__ rowptr, int* __restrict__ cursor, int N, int E) {
    int i = blockIdx.x * 256 + threadIdx.x;
    if (i < N) {
        int r = part[i] + bsum[blockIdx.x];
        rowptr[i] = r; cursor[i] = r;
    }
    if (i == 0) rowptr[N] = E;
}

__global__ void k_scatter(const int* __restrict__ src, const int* __restrict__ dst,
                          const int* __restrict__ et, int* __restrict__ cursor,
                          unsigned* __restrict__ erec, int E, int halfE) {
    int e = blockIdx.x * blockDim.x + threadIdx.x;
    if (e < E) {
        int d = dst[e];
        int pos = atomicAdd(&cursor[d], 1);
        unsigned rec = (unsigned)src[e] | ((unsigned)et[e] << 16)
                     | ((e >= halfE) ? 0x80000000u : 0u);
        erec[pos] = rec;
    }
}

// ---- dtype prep (merged) ---------------------------------------------------

__global__ void k_cvt3(const float* __restrict__ s0, unsigned short* __restrict__ d0, long n0,
                       const float* __restrict__ s1, unsigned short* __restrict__ d1, long n1,
                       const float* __restrict__ s2, unsigned short* __restrict__ d2, long n2) {
    long i = (long)blockIdx.x * blockDim.x + threadIdx.x;
    const float* s; unsigned short* d; long j = i;
    if (j < n0) { s = s0; d = d0; }
    else {
        j -= n0;
        if (j < n1) { s = s1; d = d1; }
        else { j -= n1; if (j >= n2) return; s = s2; d = d2; }
    }
    float4 v = ((const float4*)s)[j];
    ushort4 o;
    o.x = f2b(v.x); o.y = f2b(v.y); o.z = f2b(v.z); o.w = f2b(v.w);
    ((ushort4*)d)[j] = o;
}

// Repack 7 W[256][256] (row-major f32) into MFMA-B fragment layout bf16:
// out[mi][((kg*16+nn)*64 + l)*8 + j] = W[kg*32 + (l>>4)*8 + j][nn*16 + (l&15)]
__global__ void k_wfrag7(const float* __restrict__ w0, const float* __restrict__ w1,
                         const float* __restrict__ w2, const float* __restrict__ w3,
                         const float* __restrict__ w4, const float* __restrict__ w5,
                         const float* __restrict__ w6, unsigned short* __restrict__ out) {
    int o = blockIdx.x * 256 + threadIdx.x;      // grid = 7*65536/256
    int mi = o >> 16;
    int r  = o & 65535;
    const float* W = (mi == 0) ? w0 : (mi == 1) ? w1 : (mi == 2) ? w2 :
                     (mi == 3) ? w3 : (mi == 4) ? w4 : (mi == 5) ? w5 : w6;
    int j  = r & 7;
    int l  = (r >> 3) & 63;
    int nn = (r >> 9) & 15;
    int kg = r >> 13;
    int k = kg * 32 + (l >> 4) * 8 + j;
    int n = nn * 16 + (l & 15);
    out[o] = f2b(W[k * 256 + n]);
}

// ---- CSR gather aggregation (no atomics), 2-edge software pipeline --------

__global__ __launch_bounds__(256)
void k_agg(const unsigned short* __restrict__ xb, const unsigned short* __restrict__ relb,
           const int* __restrict__ rowptr, const unsigned* __restrict__ erec,
           const float* __restrict__ norm,
           unsigned short* __restrict__ sIn, unsigned short* __restrict__ sOut,
           int N, int D)
{
    const int w = threadIdx.x >> 6, l = threadIdx.x & 63;
    const int v = blockIdx.x * 4 + w;
    if (v >= N) return;
    const int rs = rowptr[v], re = rowptr[v + 1];
    const float nm = norm[v];

    float ai0 = 0, ai1 = 0, ai2 = 0, ai3 = 0;
    float ao0 = 0, ao1 = 0, ao2 = 0, ao3 = 0;

    unsigned c0 = (rs     < re) ? erec[rs]     : 0u;
    unsigned c1 = (rs + 1 < re) ? erec[rs + 1] : 0u;
    int i = rs;
    while (i + 2 <= re) {
        unsigned n0 = (i + 2 < re) ? erec[i + 2] : 0u;
        unsigned n1 = (i + 3 < re) ? erec[i + 3] : 0u;
        // two independent gather pairs in flight
        ushort4 x0 = *(const ushort4*)(xb   + (size_t)(c0 & 0xffff) * D + l * 4);
        ushort4 r0 = *(const ushort4*)(relb + (size_t)((c0 >> 16) & 0x7fff) * D + l * 4);
        ushort4 x1 = *(const ushort4*)(xb   + (size_t)(c1 & 0xffff) * D + l * 4);
        ushort4 r1 = *(const ushort4*)(relb + (size_t)((c1 >> 16) & 0x7fff) * D + l * 4);
        float p0 = b2f(x0.x) * b2f(r0.x), p1 = b2f(x0.y) * b2f(r0.y);
        float p2 = b2f(x0.z) * b2f(r0.z), p3 = b2f(x0.w) * b2f(r0.w);
        if (c0 >> 31) { ao0 += p0; ao1 += p1; ao2 += p2; ao3 += p3; }
        else          { ai0 += p0; ai1 += p1; ai2 += p2; ai3 += p3; }
        p0 = b2f(x1.x) * b2f(r1.x); p1 = b2f(x1.y) * b2f(r1.y);
        p2 = b2f(x1.z) * b2f(r1.z); p3 = b2f(x1.w) * b2f(r1.w);
        if (c1 >> 31) { ao0 += p0; ao1 += p1; ao2 += p2; ao3 += p3; }
        else          { ai0 += p0; ai1 += p1; ai2 += p2; ai3 += p3; }
        c0 = n0; c1 = n1; i += 2;
    }
    if (i < re) {
        ushort4 x0 = *(const ushort4*)(xb   + (size_t)(c0 & 0xffff) * D + l * 4);
        ushort4 r0 = *(const ushort4*)(relb + (size_t)((c0 >> 16) & 0x7fff) * D + l * 4);
        float p0 = b2f(x0.x) * b2f(r0.x), p1 = b2f(x0.y) * b2f(r0.y);
        float p2 = b2f(x0.z) * b2f(r0.z), p3 = b2f(x0.w) * b2f(r0.w);
        if (c0 >> 31) { ao0 += p0; ao1 += p1; ao2 += p2; ao3 += p3; }
        else          { ai0 += p0; ai1 += p1; ai2 += p2; ai3 += p3; }
    }

    ushort4 oi, oo;
    oi.x = f2b(ai0 * nm); oi.y = f2b(ai1 * nm); oi.z = f2b(ai2 * nm); oi.w = f2b(ai3 * nm);
    oo.x = f2b(ao0 * nm); oo.y = f2b(ao1 * nm); oo.z = f2b(ao2 * nm); oo.w = f2b(ao3 * nm);
    *(ushort4*)(sIn  + (size_t)v * D + l * 4) = oi;
    *(ushort4*)(sOut + (size_t)v * D + l * 4) = oo;
}

// ---- fused node GEMM -------------------------------------------------------
// K = 768 over [a0|a1|a2]; epilogue h = bf16(a0[row]) + res*tanh(acc+bias).
// HEAD=false: h -> outB (bf16).
// HEAD=true : h -> swizzled LDS tile, then out = h @ WfMu + mub -> outF (f32).
//
// One K-step per iteration: compute tile s from LDS buf[s&1]; issue global
// loads for tile s+2; ds_write tile s+1 into buf[(s+1)&1]; raw s_barrier
// (no vmem drain -- prefetch stays in flight across barriers).

#define GITER(S, AtC, AtN, Rc0, Rc1, Rn0, Rn1)                                   \
  {                                                                              \
    const int p_ = (S) >> 2, cb_ = (S) & 3;                                      \
    const unsigned short* __restrict__ Wp_ = Wf + (size_t)p_ * 65536;            \
    _Pragma("unroll")                                                            \
    for (int kk = 0; kk < 2; ++kk) {                                             \
      const int kg_ = cb_ * 2 + kk;                                              \
      bf16x8 a_[4], b_[4];                                                       \
      _Pragma("unroll")                                                          \
      for (int m = 0; m < 4; ++m) {                                              \
        int rm = 16 * m + lr;                                                    \
        int ch = (kk * 4 + lq) ^ (rm & 7);                                       \
        a_[m] = *(const bf16x8*)(&AtC[rm * 64 + ch * 8]);                        \
      }                                                                          \
      _Pragma("unroll")                                                          \
      for (int n = 0; n < 4; ++n)                                                \
        b_[n] = *(const bf16x8*)(Wp_ + (((kg_ * 16 + (w * 4 + n)) * 64 + l) * 8));\
      _Pragma("unroll")                                                          \
      for (int m = 0; m < 4; ++m)                                                \
        _Pragma("unroll")                                                        \
        for (int n = 0; n < 4; ++n)                                              \
          acc[m][n] = __builtin_amdgcn_mfma_f32_16x16x32_bf16(a_[m], b_[n], acc[m][n], 0, 0, 0); \
    }                                                                            \
    if ((S) + 2 < NT) {                                                          \
      int p2_ = ((S) + 2) >> 2, cb2_ = ((S) + 2) & 3;                            \
      const unsigned short* ap_ = (p2_ == 0) ? a0 : ((p2_ == 1) ? a1 : a2);      \
      Rn0 = *(const uint4*)(ap_ + g0 + cb2_ * 64);                               \
      Rn1 = *(const uint4*)(ap_ + g1 + cb2_ * 64);                               \
    }                                                                            \
    if ((S) + 1 < NT) {                                                          \
      *(uint4*)(&AtN[wo0]) = Rc0;                                                \
      *(uint4*)(&AtN[wo1]) = Rc1;                                                \
    }                                                                            \
    asm volatile("s_waitcnt lgkmcnt(0)" ::: "memory");                           \
    __builtin_amdgcn_sched_barrier(0);                                           \
    __builtin_amdgcn_s_barrier();                                                \
    __builtin_amdgcn_sched_barrier(0);                                           \
  }

template <bool HEAD>
__global__ __launch_bounds__(256, 3)
void k_gemm(const unsigned short* __restrict__ a0,
            const unsigned short* __restrict__ a1,
            const unsigned short* __restrict__ a2,
            const unsigned short* __restrict__ Wf,    // frag layout, 3*65536
            const float* __restrict__ bias,
            const float* __restrict__ resPtr,
            const unsigned short* __restrict__ WfMu,  // frag layout, 65536 (HEAD)
            const float* __restrict__ mub,            // [256] (HEAD)
            float* __restrict__ outF,                 // [N,256] f32 (HEAD)
            unsigned short* __restrict__ outB,        // [N,256] bf16 (!HEAD)
            int N, int D)
{
    __shared__ unsigned short lds[HEAD ? 16384 : 8192];
    unsigned short* At0 = lds;
    unsigned short* At1 = lds + 4096;

    const int t = threadIdx.x;
    const int rBase = blockIdx.x * 64;
    const int NT = 12;

    const int w  = t >> 6;
    const int l  = t & 63;
    const int lr = l & 15;
    const int lq = l >> 4;

    // staging geometry
    const int rS0 = t >> 3;
    const int rS1 = rS0 + 32;
    const int cS  = t & 7;
    const int wo0 = rS0 * 64 + ((cS ^ (rS0 & 7)) * 8);
    const int wo1 = rS1 * 64 + ((cS ^ (rS1 & 7)) * 8);
    const size_t g0 = (size_t)min(rBase + rS0, N - 1) * D + cS * 8;
    const size_t g1 = (size_t)min(rBase + rS1, N - 1) * D + cS * 8;

    f32x4 acc[4][4] = {};
    uint4 Ra0, Ra1, Rb0, Rb1;

    // prologue: tile0 -> Ra -> At0; tile1 -> Rb (stays in flight)
    Ra0 = *(const uint4*)(a0 + g0);
    Ra1 = *(const uint4*)(a0 + g1);
    Rb0 = *(const uint4*)(a0 + g0 + 64);
    Rb1 = *(const uint4*)(a0 + g1 + 64);
    *(uint4*)(&At0[wo0]) = Ra0;               // compiler waits only tile0 (counted)
    *(uint4*)(&At0[wo1]) = Ra1;
    asm volatile("s_waitcnt lgkmcnt(0)" ::: "memory");
    __builtin_amdgcn_sched_barrier(0);
    __builtin_amdgcn_s_barrier();
    __builtin_amdgcn_sched_barrier(0);

    for (int s = 0; s < NT; s += 2) {
        GITER(s,     At0, At1, Rb0, Rb1, Ra0, Ra1);
        GITER(s + 1, At1, At0, Ra0, Ra1, Rb0, Rb1);
    }

    // ---- epilogue: h = residual + res*tanh(acc + bias) ----
    const int rb4 = lq * 4;
    const float resv = resPtr[0];
    #pragma unroll
    for (int m = 0; m < 4; ++m) {
        #pragma unroll
        for (int i = 0; i < 4; ++i) {
            int row = rBase + 16 * m + rb4 + i;
            if (row < N) {
                size_t base = (size_t)row * D + w * 64 + lr;
                int r6 = 16 * m + rb4 + i;
                #pragma unroll
                for (int n = 0; n < 4; ++n) {
                    int   c = w * 64 + lr + 16 * n;
                    float v = acc[m][n][i] + bias[c];
                    float h = b2f(a0[base + 16 * n]) + resv * ftanh(v);
                    if (HEAD) {
                        lds[r6 * 256 + (c ^ ((r6 & 7) << 3))] = f2b(h);
                    } else {
                        outB[base + 16 * n] = f2b(h);
                    }
                }
            }
        }
    }

    if (HEAD) {
        __syncthreads();                      // h2 tile complete
        #pragma unroll
        for (int m = 0; m < 4; ++m)
            #pragma unroll
            for (int n = 0; n < 4; ++n)
                acc[m][n] = (f32x4){0.f, 0.f, 0.f, 0.f};

        #pragma unroll
        for (int s2 = 0; s2 < 4; ++s2) {
            #pragma unroll
            for (int kk = 0; kk < 2; ++kk) {
                const int kg = s2 * 2 + kk;
                bf16x8 a_[4], b_[4];
                #pragma unroll
                for (int m = 0; m < 4; ++m) {
                    int rm = 16 * m + lr;
                    int ch = (s2 * 8 + kk * 4 + lq) ^ (rm & 7);
                    a_[m] = *(const bf16x8*)(&lds[rm * 256 + ch * 8]);
                }
                #pragma unroll
                for (int n = 0; n < 4; ++n)
                    b_[n] = *(const bf16x8*)(WfMu + (((kg * 16 + (w * 4 + n)) * 64 + l) * 8));
                #pragma unroll
                for (int m = 0; m < 4; ++m)
                    #pragma unroll
                    for (int n = 0; n < 4; ++n)
                        acc[m][n] = __builtin_amdgcn_mfma_f32_16x16x32_bf16(a_[m], b_[n], acc[m][n], 0, 0, 0);
            }
        }

        #pragma unroll
        for (int m = 0; m < 4; ++m) {
            #pragma unroll
            for (int i = 0; i < 4; ++i) {
                int row = rBase + 16 * m + rb4 + i;
                if (row < N) {
                    size_t base = (size_t)row * D + w * 64 + lr;
                    #pragma unroll
                    for (int n = 0; n < 4; ++n) {
                        int c = w * 64 + lr + 16 * n;
                        outF[base + 16 * n] = acc[m][n][i] + mub[c];
                    }
                }
            }
        }
    }
}

// ---------------------------------------------------------------------------

extern "C" void kernel_launch(void* const* d_in, const int* in_sizes, int n_in,
                              void* d_out, int out_size, void* d_ws, size_t ws_size,
                              hipStream_t stream)
{
    const float* emb  = (const float*)d_in[0];
    const int*   ei   = (const int*)  d_in[1];
    const int*   et   = (const int*)  d_in[2];
    const float* rel1 = (const float*)d_in[3];
    const float* Wi1  = (const float*)d_in[4];
    const float* Wo1  = (const float*)d_in[5];
    const float* Wl1  = (const float*)d_in[6];
    const float* b1   = (const float*)d_in[7];
    const float* rel2 = (const float*)d_in[8];
    const float* Wi2  = (const float*)d_in[9];
    const float* Wo2  = (const float*)d_in[10];
    const float* Wl2  = (const float*)d_in[11];
    const float* b2   = (const float*)d_in[12];
    const float* res  = (const float*)d_in[13];
    const float* muw  = (const float*)d_in[14];
    const float* mub  = (const float*)d_in[15];

    const int D = in_sizes[7];          // 256
    const int N = in_sizes[0] / D;      // 50000
    const int E = in_sizes[2];          // 320000
    const int R = in_sizes[3] / D;      // 400
    const int halfE = E / 2;
    const int* srcA = ei;
    const int* dstA = ei + E;
    const size_t DD = (size_t)D * D;

    char* ws = (char*)d_ws;
    size_t off = 0;
    auto alloc = [&](size_t bytes) -> char* {
        char* p = ws + off; off += (bytes + 255) & ~(size_t)255; return p;
    };
    const int nb1 = (N + 255) / 256;

    float*          norm   = (float*)          alloc((size_t)N * 4);
    int*            cnt    = (int*)            alloc((size_t)N * 4);
    int*            rowptr = (int*)            alloc((size_t)(N + 1) * 4);
    int*            cursor = (int*)            alloc((size_t)N * 4);
    int*            part   = (int*)            alloc((size_t)N * 4);
    int*            bsum   = (int*)            alloc(1024);
    unsigned*       erec   = (unsigned*)       alloc((size_t)E * 4);
    unsigned short* xb     = (unsigned short*) alloc((size_t)N * D * 2);
    unsigned short* h1b    = (unsigned short*) alloc((size_t)N * D * 2);
    unsigned short* sIn    = (unsigned short*) alloc((size_t)N * D * 2);
    unsigned short* sOut   = (unsigned short*) alloc((size_t)N * D * 2);
    unsigned short* r1b    = (unsigned short*) alloc((size_t)R * D * 2);
    unsigned short* r2b    = (unsigned short*) alloc((size_t)R * D * 2);
    unsigned short* fAll   = (unsigned short*) alloc(7 * DD * 2);
    if (off > ws_size) return;

    unsigned short* fW1 = fAll;            // [Wl1, Wi1, Wo1]
    unsigned short* fW2 = fAll + 3 * DD;   // [Wl2, Wi2, Wo2]
    unsigned short* fMu = fAll + 6 * DD;

    // --- CSR + norm ---
    hipMemsetAsync(cnt, 0, (size_t)N * 4, stream);
    k_hist   <<<(E + 255) / 256, 256, 0, stream>>>(dstA, cnt, E);
    k_norm   <<<nb1, 256, 0, stream>>>(cnt, norm, N);
    k_scan1  <<<nb1, 256, 0, stream>>>(cnt, part, bsum, N);
    k_scan2  <<<1,   256, 0, stream>>>(bsum, nb1);
    k_scan3  <<<nb1, 256, 0, stream>>>(part, bsum, rowptr, cursor, N, E);
    k_scatter<<<(E + 255) / 256, 256, 0, stream>>>(srcA, dstA, et, cursor, erec, E, halfE);

    // --- dtype prep ---
    long nd4 = (long)N * D / 4, rd4 = (long)R * D / 4;
    long tot4 = nd4 + 2 * rd4;
    k_cvt3<<<(int)((tot4 + 255) / 256), 256, 0, stream>>>(
        emb, xb, nd4, rel1, r1b, rd4, rel2, r2b, rd4);
    k_wfrag7<<<(int)(7 * DD / 256), 256, 0, stream>>>(
        Wl1, Wi1, Wo1, Wl2, Wi2, Wo2, muw, fAll);

    const int AB = (N + 3) / 4;
    const int NB = (N + 63) / 64;

    // --- layer 1 ---
    k_agg<<<AB, 256, 0, stream>>>(xb, r1b, rowptr, erec, norm, sIn, sOut, N, D);
    k_gemm<false><<<NB, 256, 0, stream>>>(xb, sIn, sOut, fW1, b1, res,
                                          nullptr, nullptr, nullptr, h1b, N, D);

    // --- layer 2 + head (fused) ---
    k_agg<<<AB, 256, 0, stream>>>(h1b, r2b, rowptr, erec, norm, sIn, sOut, N, D);
    k_gemm<true><<<NB, 256, 0, stream>>>(h1b, sIn, sOut, fW2, b2, res,
                                         fMu, mub, (float*)d_out, nullptr, N, D);
}

// Round 7
// 240.725 us; speedup vs baseline: 3.2661x; 1.0121x over previous
//
#include <hip/hip_runtime.h>
#include <hip/hip_bf16.h>
#include <cstdint>
#include <cstddef>

// ---------------------------------------------------------------------------
// MGCN (2-layer relational GCN + linear head).
//
//   s_in[v]  = norm[v] * sum_{first-half edges,  dst=v} x[src]*rel[ty]
//   s_out[v] = norm[v] * sum_{second-half edges, dst=v} x[src]*rel[ty]
//   h        = x + res * tanh( [x|s_in|s_out] @ [W_loop;W_in;W_out] + b )
//   out      = h2 @ mu_w + mu_b        (fused into the layer-2 kernel)
//
// GEMM: 64-row tiles, K=768 in 12 BK=64 steps, 3-deep register A-prefetch,
// double-buffered LDS, raw s_barrier fenced on BOTH sides (lgkmcnt asm w/
// memory clobber before, sched_barrier(0) after -- s_barrier alone is not a
// compiler fence).  Coalesced LDS-staged epilogues for both kernel flavors.
// ---------------------------------------------------------------------------

typedef short bf16x8 __attribute__((ext_vector_type(8)));
typedef float f32x4  __attribute__((ext_vector_type(4)));

__device__ __forceinline__ float b2f(unsigned short u) {
    union { unsigned u32; float f; } c; c.u32 = ((unsigned)u) << 16; return c.f;
}
__device__ __forceinline__ unsigned short f2b(float f) {
    union { float f; unsigned u; } c; c.f = f;
    unsigned r = c.u + 0x7FFFu + ((c.u >> 16) & 1u);   // RNE
    return (unsigned short)(r >> 16);
}
__device__ __forceinline__ float ftanh(float x) {
    float e = __expf(2.0f * x);
    return 1.0f - __fdividef(2.0f, e + 1.0f);
}

// ---- CSR construction ------------------------------------------------------

__global__ void k_hist(const int* __restrict__ dst, int* __restrict__ cnt, int E) {
    int i = blockIdx.x * blockDim.x + threadIdx.x;
    if (i < E) atomicAdd(&cnt[dst[i]], 1);
}

__global__ void k_norm(const int* __restrict__ cnt, float* __restrict__ norm, int N) {
    int i = blockIdx.x * blockDim.x + threadIdx.x;
    if (i < N) norm[i] = 1.0f / fmaxf((float)cnt[i], 1.0f);
}

__global__ void k_scan1(const int* __restrict__ cnt, int* __restrict__ part,
                        int* __restrict__ bsum, int N) {
    __shared__ int s[256];
    int i = blockIdx.x * 256 + threadIdx.x;
    int v = (i < N) ? cnt[i] : 0;
    s[threadIdx.x] = v; __syncthreads();
    #pragma unroll
    for (int o = 1; o < 256; o <<= 1) {
        int t = (threadIdx.x >= o) ? s[threadIdx.x - o] : 0;
        __syncthreads();
        s[threadIdx.x] += t;
        __syncthreads();
    }
    if (i < N) part[i] = s[threadIdx.x] - v;
    if (threadIdx.x == 255) bsum[blockIdx.x] = s[255];
}

__global__ void k_scan2(int* __restrict__ bsum, int nb) {
    __shared__ int s[256];
    int v = (threadIdx.x < nb) ? bsum[threadIdx.x] : 0;
    s[threadIdx.x] = v; __syncthreads();
    #pragma unroll
    for (int o = 1; o < 256; o <<= 1) {
        int t = (threadIdx.x >= o) ? s[threadIdx.x - o] : 0;
        __syncthreads();
        s[threadIdx.x] += t;
        __syncthreads();
    }
    if (threadIdx.x < nb) bsum[threadIdx.x] = s[threadIdx.x] - v;
}

__global__ void k_scan3(const int* __restrict__ part, const int* __restrict__ bsum,
                        int* __restrict__ rowptr, int* __restrict__ cursor, int N, int E) {
    int i = blockIdx.x * 256 + threadIdx.x;
    if (i < N) {
        int r = part[i] + bsum[blockIdx.x];
        rowptr[i] = r; cursor[i] = r;
    }
    if (i == 0) rowptr[N] = E;
}

__global__ void k_scatter(const int* __restrict__ src, const int* __restrict__ dst,
                          const int* __restrict__ et, int* __restrict__ cursor,
                          unsigned* __restrict__ erec, int E, int halfE) {
    int e = blockIdx.x * blockDim.x + threadIdx.x;
    if (e < E) {
        int d = dst[e];
        int pos = atomicAdd(&cursor[d], 1);
        unsigned rec = (unsigned)src[e] | ((unsigned)et[e] << 16)
                     | ((e >= halfE) ? 0x80000000u : 0u);
        erec[pos] = rec;
    }
}

// ---- dtype prep ------------------------------------------------------------

__global__ void k_cvt3(const float* __restrict__ s0, unsigned short* __restrict__ d0, long n0,
                       const float* __restrict__ s1, unsigned short* __restrict__ d1, long n1,
                       const float* __restrict__ s2, unsigned short* __restrict__ d2, long n2) {
    long i = (long)blockIdx.x * blockDim.x + threadIdx.x;
    const float* s; unsigned short* d; long j = i;
    if (j < n0) { s = s0; d = d0; }
    else {
        j -= n0;
        if (j < n1) { s = s1; d = d1; }
        else { j -= n1; if (j >= n2) return; s = s2; d = d2; }
    }
    float4 v = ((const float4*)s)[j];
    ushort4 o;
    o.x = f2b(v.x); o.y = f2b(v.y); o.z = f2b(v.z); o.w = f2b(v.w);
    ((ushort4*)d)[j] = o;
}

// Repack 7 W[256][256] (row-major f32) into MFMA-B fragment layout bf16:
// out[mi][((kg*16+nn)*64 + l)*8 + j] = W[kg*32 + (l>>4)*8 + j][nn*16 + (l&15)]
__global__ void k_wfrag7(const float* __restrict__ w0, const float* __restrict__ w1,
                         const float* __restrict__ w2, const float* __restrict__ w3,
                         const float* __restrict__ w4, const float* __restrict__ w5,
                         const float* __restrict__ w6, unsigned short* __restrict__ out) {
    int o = blockIdx.x * 256 + threadIdx.x;      // grid = 7*65536/256
    int mi = o >> 16;
    int r  = o & 65535;
    const float* W = (mi == 0) ? w0 : (mi == 1) ? w1 : (mi == 2) ? w2 :
                     (mi == 3) ? w3 : (mi == 4) ? w4 : (mi == 5) ? w5 : w6;
    int j  = r & 7;
    int l  = (r >> 3) & 63;
    int nn = (r >> 9) & 15;
    int kg = r >> 13;
    int k = kg * 32 + (l >> 4) * 8 + j;
    int n = nn * 16 + (l & 15);
    out[o] = f2b(W[k * 256 + n]);
}

// ---- CSR gather aggregation (no atomics), 4-edge software pipeline --------

__global__ __launch_bounds__(256)
void k_agg(const unsigned short* __restrict__ xb, const unsigned short* __restrict__ relb,
           const int* __restrict__ rowptr, const unsigned* __restrict__ erec,
           const float* __restrict__ norm,
           unsigned short* __restrict__ sIn, unsigned short* __restrict__ sOut,
           int N, int D)
{
    const int w = threadIdx.x >> 6, l = threadIdx.x & 63;
    const int v = blockIdx.x * 4 + w;
    if (v >= N) return;
    const int rs = rowptr[v], re = rowptr[v + 1];
    const float nm = norm[v];

    float ai0 = 0, ai1 = 0, ai2 = 0, ai3 = 0;
    float ao0 = 0, ao1 = 0, ao2 = 0, ao3 = 0;

    unsigned c0 = (rs     < re) ? erec[rs]     : 0u;
    unsigned c1 = (rs + 1 < re) ? erec[rs + 1] : 0u;
    unsigned c2 = (rs + 2 < re) ? erec[rs + 2] : 0u;
    unsigned c3 = (rs + 3 < re) ? erec[rs + 3] : 0u;
    int i = rs;
    while (i + 4 <= re) {
        unsigned m0 = (i + 4 < re) ? erec[i + 4] : 0u;
        unsigned m1 = (i + 5 < re) ? erec[i + 5] : 0u;
        unsigned m2 = (i + 6 < re) ? erec[i + 6] : 0u;
        unsigned m3 = (i + 7 < re) ? erec[i + 7] : 0u;
        ushort4 x0 = *(const ushort4*)(xb   + (size_t)(c0 & 0xffff) * D + l * 4);
        ushort4 r0 = *(const ushort4*)(relb + (size_t)((c0 >> 16) & 0x7fff) * D + l * 4);
        ushort4 x1 = *(const ushort4*)(xb   + (size_t)(c1 & 0xffff) * D + l * 4);
        ushort4 r1 = *(const ushort4*)(relb + (size_t)((c1 >> 16) & 0x7fff) * D + l * 4);
        ushort4 x2 = *(const ushort4*)(xb   + (size_t)(c2 & 0xffff) * D + l * 4);
        ushort4 r2 = *(const ushort4*)(relb + (size_t)((c2 >> 16) & 0x7fff) * D + l * 4);
        ushort4 x3 = *(const ushort4*)(xb   + (size_t)(c3 & 0xffff) * D + l * 4);
        ushort4 r3 = *(const ushort4*)(relb + (size_t)((c3 >> 16) & 0x7fff) * D + l * 4);
        float p0, p1, p2, p3;
        p0 = b2f(x0.x)*b2f(r0.x); p1 = b2f(x0.y)*b2f(r0.y);
        p2 = b2f(x0.z)*b2f(r0.z); p3 = b2f(x0.w)*b2f(r0.w);
        if (c0 >> 31) { ao0 += p0; ao1 += p1; ao2 += p2; ao3 += p3; }
        else          { ai0 += p0; ai1 += p1; ai2 += p2; ai3 += p3; }
        p0 = b2f(x1.x)*b2f(r1.x); p1 = b2f(x1.y)*b2f(r1.y);
        p2 = b2f(x1.z)*b2f(r1.z); p3 = b2f(x1.w)*b2f(r1.w);
        if (c1 >> 31) { ao0 += p0; ao1 += p1; ao2 += p2; ao3 += p3; }
        else          { ai0 += p0; ai1 += p1; ai2 += p2; ai3 += p3; }
        p0 = b2f(x2.x)*b2f(r2.x); p1 = b2f(x2.y)*b2f(r2.y);
        p2 = b2f(x2.z)*b2f(r2.z); p3 = b2f(x2.w)*b2f(r2.w);
        if (c2 >> 31) { ao0 += p0; ao1 += p1; ao2 += p2; ao3 += p3; }
        else          { ai0 += p0; ai1 += p1; ai2 += p2; ai3 += p3; }
        p0 = b2f(x3.x)*b2f(r3.x); p1 = b2f(x3.y)*b2f(r3.y);
        p2 = b2f(x3.z)*b2f(r3.z); p3 = b2f(x3.w)*b2f(r3.w);
        if (c3 >> 31) { ao0 += p0; ao1 += p1; ao2 += p2; ao3 += p3; }
        else          { ai0 += p0; ai1 += p1; ai2 += p2; ai3 += p3; }
        c0 = m0; c1 = m1; c2 = m2; c3 = m3; i += 4;
    }
    #pragma unroll
    for (int j = 0; j < 3; ++j) {
        if (i + j < re) {
            unsigned cur = (j == 0) ? c0 : (j == 1) ? c1 : c2;
            ushort4 x0 = *(const ushort4*)(xb   + (size_t)(cur & 0xffff) * D + l * 4);
            ushort4 r0 = *(const ushort4*)(relb + (size_t)((cur >> 16) & 0x7fff) * D + l * 4);
            float p0 = b2f(x0.x)*b2f(r0.x), p1 = b2f(x0.y)*b2f(r0.y);
            float p2 = b2f(x0.z)*b2f(r0.z), p3 = b2f(x0.w)*b2f(r0.w);
            if (cur >> 31) { ao0 += p0; ao1 += p1; ao2 += p2; ao3 += p3; }
            else           { ai0 += p0; ai1 += p1; ai2 += p2; ai3 += p3; }
        }
    }

    ushort4 oi, oo;
    oi.x = f2b(ai0 * nm); oi.y = f2b(ai1 * nm); oi.z = f2b(ai2 * nm); oi.w = f2b(ai3 * nm);
    oo.x = f2b(ao0 * nm); oo.y = f2b(ao1 * nm); oo.z = f2b(ao2 * nm); oo.w = f2b(ao3 * nm);
    *(ushort4*)(sIn  + (size_t)v * D + l * 4) = oi;
    *(ushort4*)(sOut + (size_t)v * D + l * 4) = oo;
}

// ---- fused node GEMM -------------------------------------------------------
// Step s: ds_write tile s+1 (regs loaded at s-2); MFMA tile s from At[s&1];
// issue loads for tile s+3; lgkmcnt(0) fence; s_barrier; sched_barrier(0).
// Vmem never drained in the loop.

#define GIT(S, AtC, AtN, Rw0, Rw1, Rl0, Rl1)                                    \
  do {                                                                          \
    if ((S) + 1 < 12) {                                                         \
      *(uint4*)(&AtN[wo0]) = Rw0;                                               \
      *(uint4*)(&AtN[wo1]) = Rw1;                                               \
    }                                                                           \
    {                                                                           \
      const int p_ = (S) >> 2, cb_ = (S) & 3;                                   \
      const unsigned short* __restrict__ Wp_ = Wf + (size_t)p_ * 65536;         \
      _Pragma("unroll")                                                         \
      for (int kk_ = 0; kk_ < 2; ++kk_) {                                       \
        const int kg_ = cb_ * 2 + kk_;                                          \
        bf16x8 a_[4], b_[4];                                                    \
        _Pragma("unroll")                                                       \
        for (int m_ = 0; m_ < 4; ++m_) {                                        \
          int rm_ = 16 * m_ + lr;                                               \
          int ch_ = (kk_ * 4 + lq) ^ (rm_ & 7);                                 \
          a_[m_] = *(const bf16x8*)(&AtC[rm_ * 64 + ch_ * 8]);                  \
        }                                                                       \
        _Pragma("unroll")                                                       \
        for (int n_ = 0; n_ < 4; ++n_) {                                        \
          b_[n_] = *(const bf16x8*)(Wp_ + (((kg_ * 16 + (w * 4 + n_)) * 64 + l) * 8)); \
        }                                                                       \
        _Pragma("unroll")                                                       \
        for (int m_ = 0; m_ < 4; ++m_) {                                        \
          _Pragma("unroll")                                                     \
          for (int n_ = 0; n_ < 4; ++n_) {                                      \
            acc[m_][n_] = __builtin_amdgcn_mfma_f32_16x16x32_bf16(a_[m_], b_[n_], acc[m_][n_], 0, 0, 0); \
          }                                                                     \
        }                                                                       \
      }                                                                         \
    }                                                                           \
    if ((S) + 3 < 12) {                                                         \
      const int p3_ = ((S) + 3) >> 2, cb3_ = ((S) + 3) & 3;                     \
      const unsigned short* ap_ = (p3_ == 0) ? a0 : ((p3_ == 1) ? a1 : a2);     \
      Rl0 = *(const uint4*)(ap_ + g0 + cb3_ * 64);                              \
      Rl1 = *(const uint4*)(ap_ + g1 + cb3_ * 64);                              \
    }                                                                           \
    asm volatile("s_waitcnt lgkmcnt(0)" ::: "memory");                          \
    __builtin_amdgcn_sched_barrier(0);                                          \
    __builtin_amdgcn_s_barrier();                                               \
    __builtin_amdgcn_sched_barrier(0);                                          \
  } while (0)

template <bool HEAD>
__global__ __launch_bounds__(256, 4)
void k_gemm(const unsigned short* __restrict__ a0,
            const unsigned short* __restrict__ a1,
            const unsigned short* __restrict__ a2,
            const unsigned short* __restrict__ Wf,    // frag layout, 3*65536
            const float* __restrict__ bias,
            const float* __restrict__ resPtr,
            const unsigned short* __restrict__ WfMu,  // frag layout (HEAD)
            const float* __restrict__ mub,            // [256] (HEAD)
            float* __restrict__ outF,                 // [N,256] f32 (HEAD)
            unsigned short* __restrict__ outB,        // [N,256] bf16 (!HEAD)
            int N, int D)
{
    __shared__ unsigned short lds[HEAD ? 16384 : 8192];
    unsigned short* At0 = lds;
    unsigned short* At1 = lds + 4096;

    const int t = threadIdx.x;
    const int rBase = blockIdx.x * 64;

    const int w  = t >> 6;
    const int l  = t & 63;
    const int lr = l & 15;
    const int lq = l >> 4;

    // staging geometry
    const int rS0 = t >> 3;
    const int rS1 = rS0 + 32;
    const int cS  = t & 7;
    const int wo0 = rS0 * 64 + ((cS ^ (rS0 & 7)) * 8);
    const int wo1 = rS1 * 64 + ((cS ^ (rS1 & 7)) * 8);
    const size_t g0 = (size_t)min(rBase + rS0, N - 1) * D + cS * 8;
    const size_t g1 = (size_t)min(rBase + rS1, N - 1) * D + cS * 8;

    f32x4 acc[4][4] = {};
    uint4 Ra0, Ra1, Rb0, Rb1, Rc0, Rc1;

    // prologue: tiles 0,1,2 in flight; tile 0 -> At0
    Ra0 = *(const uint4*)(a0 + g0);
    Ra1 = *(const uint4*)(a0 + g1);
    Rb0 = *(const uint4*)(a0 + g0 + 64);
    Rb1 = *(const uint4*)(a0 + g1 + 64);
    Rc0 = *(const uint4*)(a0 + g0 + 128);
    Rc1 = *(const uint4*)(a0 + g1 + 128);
    *(uint4*)(&At0[wo0]) = Ra0;
    *(uint4*)(&At0[wo1]) = Ra1;
    asm volatile("s_waitcnt lgkmcnt(0)" ::: "memory");
    __builtin_amdgcn_sched_barrier(0);
    __builtin_amdgcn_s_barrier();
    __builtin_amdgcn_sched_barrier(0);

    GIT(0,  At0, At1, Rb0, Rb1, Ra0, Ra1);
    GIT(1,  At1, At0, Rc0, Rc1, Rb0, Rb1);
    GIT(2,  At0, At1, Ra0, Ra1, Rc0, Rc1);
    GIT(3,  At1, At0, Rb0, Rb1, Ra0, Ra1);
    GIT(4,  At0, At1, Rc0, Rc1, Rb0, Rb1);
    GIT(5,  At1, At0, Ra0, Ra1, Rc0, Rc1);
    GIT(6,  At0, At1, Rb0, Rb1, Ra0, Ra1);
    GIT(7,  At1, At0, Rc0, Rc1, Rb0, Rb1);
    GIT(8,  At0, At1, Ra0, Ra1, Rc0, Rc1);
    GIT(9,  At1, At0, Rb0, Rb1, Ra0, Ra1);
    GIT(10, At0, At1, Rc0, Rc1, Rb0, Rb1);
    GIT(11, At1, At0, Ra0, Ra1, Rc0, Rc1);

    const int rb4 = lq * 4;
    const float resv = resPtr[0];

    if (!HEAD) {
        // ---- coalesced epilogue: stage s=res*tanh(acc+bias) in LDS halves ----
        // C is 64 rows x 128 cols bf16 per half -> 16 chunks (16B) per row.
        unsigned short* C = lds;
        #pragma unroll
        for (int half = 0; half < 2; ++half) {
            if ((w >> 1) == half) {
                #pragma unroll
                for (int m = 0; m < 4; ++m) {
                    #pragma unroll
                    for (int i = 0; i < 4; ++i) {
                        int r6 = 16 * m + rb4 + i;
                        #pragma unroll
                        for (int n = 0; n < 4; ++n) {
                            int cH = (w & 1) * 64 + lr + 16 * n;
                            float v = acc[m][n][i] + bias[half * 128 + cH];
                            C[r6 * 128 + cH] = f2b(resv * ftanh(v));
                        }
                    }
                }
            }
            __syncthreads();
            #pragma unroll
            for (int ii = 0; ii < 4; ++ii) {
                int g   = ii * 256 + t;             // 1024 chunks total
                int r   = g >> 4;                   // 16 chunks per row
                int cc  = g & 15;
                int row = rBase + r;
                if (row < N) {
                    bf16x8 sv = *(const bf16x8*)(&C[r * 128 + cc * 8]);
                    const unsigned short* ar = a0 + (size_t)row * D + half * 128 + cc * 8;
                    uint4 av = *(const uint4*)ar;
                    unsigned aw[4] = { av.x, av.y, av.z, av.w };
                    unsigned ow[4];
                    #pragma unroll
                    for (int p = 0; p < 4; ++p) {
                        float h0 = b2f((unsigned short)(aw[p] & 0xffff)) + b2f((unsigned short)sv[2 * p]);
                        float h1 = b2f((unsigned short)(aw[p] >> 16))    + b2f((unsigned short)sv[2 * p + 1]);
                        ow[p] = (unsigned)f2b(h0) | ((unsigned)f2b(h1) << 16);
                    }
                    *(uint4*)(outB + (size_t)row * D + half * 128 + cc * 8) =
                        make_uint4(ow[0], ow[1], ow[2], ow[3]);
                }
            }
            __syncthreads();
        }
    } else {
        // ---- HEAD: h2 -> swizzled LDS tile, then out = h2 @ WfMu + mub ----
        #pragma unroll
        for (int m = 0; m < 4; ++m) {
            #pragma unroll
            for (int i = 0; i < 4; ++i) {
                int row = rBase + 16 * m + rb4 + i;
                if (row < N) {
                    size_t base = (size_t)row * D + w * 64 + lr;
                    int r6 = 16 * m + rb4 + i;
                    #pragma unroll
                    for (int n = 0; n < 4; ++n) {
                        int   c = w * 64 + lr + 16 * n;
                        float v = acc[m][n][i] + bias[c];
                        float h = b2f(a0[base + 16 * n]) + resv * ftanh(v);
                        lds[r6 * 256 + (c ^ ((r6 & 7) << 3))] = f2b(h);
                    }
                }
            }
        }
        __syncthreads();
        #pragma unroll
        for (int m = 0; m < 4; ++m) {
            #pragma unroll
            for (int n = 0; n < 4; ++n)
                acc[m][n] = (f32x4){0.f, 0.f, 0.f, 0.f};
        }

        #pragma unroll
        for (int s2 = 0; s2 < 4; ++s2) {
            #pragma unroll
            for (int kk = 0; kk < 2; ++kk) {
                const int kg = s2 * 2 + kk;
                bf16x8 a_[4], b_[4];
                #pragma unroll
                for (int m = 0; m < 4; ++m) {
                    int rm = 16 * m + lr;
                    int ch = (s2 * 8 + kk * 4 + lq) ^ (rm & 7);
                    a_[m] = *(const bf16x8*)(&lds[rm * 256 + ch * 8]);
                }
                #pragma unroll
                for (int n = 0; n < 4; ++n)
                    b_[n] = *(const bf16x8*)(WfMu + (((kg * 16 + (w * 4 + n)) * 64 + l) * 8));
                #pragma unroll
                for (int m = 0; m < 4; ++m) {
                    #pragma unroll
                    for (int n = 0; n < 4; ++n)
                        acc[m][n] = __builtin_amdgcn_mfma_f32_16x16x32_bf16(a_[m], b_[n], acc[m][n], 0, 0, 0);
                }
            }
        }

        // ---- coalesced f32 store: stage acc+mub in LDS halves (64x128 f32) ----
        __syncthreads();                           // all mu-GEMM LDS reads done
        float* Cf = (float*)lds;                   // 32 KB = one 64x128 f32 half
        #pragma unroll
        for (int half = 0; half < 2; ++half) {
            if ((w >> 1) == half) {
                #pragma unroll
                for (int m = 0; m < 4; ++m) {
                    #pragma unroll
                    for (int i = 0; i < 4; ++i) {
                        int r6 = 16 * m + rb4 + i;
                        #pragma unroll
                        for (int n = 0; n < 4; ++n) {
                            int cH = (w & 1) * 64 + lr + 16 * n;
                            Cf[r6 * 128 + cH] = acc[m][n][i] + mub[half * 128 + cH];
                        }
                    }
                }
            }
            __syncthreads();
            #pragma unroll
            for (int ii = 0; ii < 8; ++ii) {
                int g   = ii * 256 + t;            // 2048 chunks total
                int r   = g >> 5;                  // 32 float4-chunks per row
                int cc  = g & 31;
                int row = rBase + r;
                if (row < N) {
                    *(float4*)(outF + (size_t)row * D + half * 128 + cc * 4) =
                        *(const float4*)(&Cf[r * 128 + cc * 4]);
                }
            }
            __syncthreads();
        }
    }
}

// ---------------------------------------------------------------------------

extern "C" void kernel_launch(void* const* d_in, const int* in_sizes, int n_in,
                              void* d_out, int out_size, void* d_ws, size_t ws_size,
                              hipStream_t stream)
{
    const float* emb  = (const float*)d_in[0];
    const int*   ei   = (const int*)  d_in[1];
    const int*   et   = (const int*)  d_in[2];
    const float* rel1 = (const float*)d_in[3];
    const float* Wi1  = (const float*)d_in[4];
    const float* Wo1  = (const float*)d_in[5];
    const float* Wl1  = (const float*)d_in[6];
    const float* b1   = (const float*)d_in[7];
    const float* rel2 = (const float*)d_in[8];
    const float* Wi2  = (const float*)d_in[9];
    const float* Wo2  = (const float*)d_in[10];
    const float* Wl2  = (const float*)d_in[11];
    const float* b2   = (const float*)d_in[12];
    const float* res  = (const float*)d_in[13];
    const float* muw  = (const float*)d_in[14];
    const float* mub  = (const float*)d_in[15];

    const int D = in_sizes[7];          // 256
    const int N = in_sizes[0] / D;      // 50000
    const int E = in_sizes[2];          // 320000
    const int R = in_sizes[3] / D;      // 400
    const int halfE = E / 2;
    const int* srcA = ei;
    const int* dstA = ei + E;
    const size_t DD = (size_t)D * D;

    char* ws = (char*)d_ws;
    size_t off = 0;
    auto alloc = [&](size_t bytes) -> char* {
        char* p = ws + off; off += (bytes + 255) & ~(size_t)255; return p;
    };
    const int nb1 = (N + 255) / 256;

    float*          norm   = (float*)          alloc((size_t)N * 4);
    int*            cnt    = (int*)            alloc((size_t)N * 4);
    int*            rowptr = (int*)            alloc((size_t)(N + 1) * 4);
    int*            cursor = (int*)            alloc((size_t)N * 4);
    int*            part   = (int*)            alloc((size_t)N * 4);
    int*            bsum   = (int*)            alloc(1024);
    unsigned*       erec   = (unsigned*)       alloc((size_t)E * 4);
    unsigned short* xb     = (unsigned short*) alloc((size_t)N * D * 2);
    unsigned short* h1b    = (unsigned short*) alloc((size_t)N * D * 2);
    unsigned short* sIn    = (unsigned short*) alloc((size_t)N * D * 2);
    unsigned short* sOut   = (unsigned short*) alloc((size_t)N * D * 2);
    unsigned short* r1b    = (unsigned short*) alloc((size_t)R * D * 2);
    unsigned short* r2b    = (unsigned short*) alloc((size_t)R * D * 2);
    unsigned short* fAll   = (unsigned short*) alloc(7 * DD * 2);
    if (off > ws_size) return;

    unsigned short* fW1 = fAll;            // [Wl1, Wi1, Wo1]
    unsigned short* fW2 = fAll + 3 * DD;   // [Wl2, Wi2, Wo2]
    unsigned short* fMu = fAll + 6 * DD;

    // --- CSR + norm ---
    hipMemsetAsync(cnt, 0, (size_t)N * 4, stream);
    k_hist   <<<(E + 255) / 256, 256, 0, stream>>>(dstA, cnt, E);
    k_norm   <<<nb1, 256, 0, stream>>>(cnt, norm, N);
    k_scan1  <<<nb1, 256, 0, stream>>>(cnt, part, bsum, N);
    k_scan2  <<<1,   256, 0, stream>>>(bsum, nb1);
    k_scan3  <<<nb1, 256, 0, stream>>>(part, bsum, rowptr, cursor, N, E);
    k_scatter<<<(E + 255) / 256, 256, 0, stream>>>(srcA, dstA, et, cursor, erec, E, halfE);

    // --- dtype prep ---
    long nd4 = (long)N * D / 4, rd4 = (long)R * D / 4;
    long tot4 = nd4 + 2 * rd4;
    k_cvt3<<<(int)((tot4 + 255) / 256), 256, 0, stream>>>(
        emb, xb, nd4, rel1, r1b, rd4, rel2, r2b, rd4);
    k_wfrag7<<<(int)(7 * DD / 256), 256, 0, stream>>>(
        Wl1, Wi1, Wo1, Wl2, Wi2, Wo2, muw, fAll);

    const int AB = (N + 3) / 4;
    const int NB = (N + 63) / 64;

    // --- layer 1 ---
    k_agg<<<AB, 256, 0, stream>>>(xb, r1b, rowptr, erec, norm, sIn, sOut, N, D);
    k_gemm<false><<<NB, 256, 0, stream>>>(xb, sIn, sOut, fW1, b1, res,
                                          nullptr, nullptr, nullptr, h1b, N, D);

    // --- layer 2 + head (fused) ---
    k_agg<<<AB, 256, 0, stream>>>(h1b, r2b, rowptr, erec, norm, sIn, sOut, N, D);
    k_gemm<true><<<NB, 256, 0, stream>>>(h1b, sIn, sOut, fW2, b2, res,
                                         fMu, mub, (float*)d_out, nullptr, N, D);
}

// Round 8
// 229.133 us; speedup vs baseline: 3.4314x; 1.0506x over previous
//
#include <hip/hip_runtime.h>
#include <hip/hip_bf16.h>
#include <cstdint>
#include <cstddef>

// ---------------------------------------------------------------------------
// MGCN (2-layer relational GCN + linear head).
//
//   s_in[v]  = norm[v] * sum_{first-half edges,  dst=v} x[src]*rel[ty]
//   s_out[v] = norm[v] * sum_{second-half edges, dst=v} x[src]*rel[ty]
//   h        = x + res * tanh( [x|s_in|s_out] @ [W_loop;W_in;W_out] + b )
//   out      = h2 @ mu_w + mu_b        (fused into the layer-2 kernel)
//
// GEMM: 64-row tiles, K=768 in 12 BK=64 steps, 3-deep register A-prefetch,
// ONE-step-ahead register B-prefetch (B consumed from regs loaded the
// previous step -> L2 latency off the critical path), double-buffered LDS,
// raw s_barrier fenced on both sides.  Coalesced LDS-staged epilogues.
// ---------------------------------------------------------------------------

typedef short bf16x8 __attribute__((ext_vector_type(8)));
typedef float f32x4  __attribute__((ext_vector_type(4)));

__device__ __forceinline__ float b2f(unsigned short u) {
    union { unsigned u32; float f; } c; c.u32 = ((unsigned)u) << 16; return c.f;
}
__device__ __forceinline__ unsigned short f2b(float f) {
    union { float f; unsigned u; } c; c.f = f;
    unsigned r = c.u + 0x7FFFu + ((c.u >> 16) & 1u);   // RNE
    return (unsigned short)(r >> 16);
}
__device__ __forceinline__ float ftanh(float x) {
    float e = __expf(2.0f * x);
    return 1.0f - __fdividef(2.0f, e + 1.0f);
}

// ---- CSR construction ------------------------------------------------------

__global__ void k_hist(const int* __restrict__ dst, int* __restrict__ cnt, int E) {
    int i = blockIdx.x * blockDim.x + threadIdx.x;
    if (i < E) atomicAdd(&cnt[dst[i]], 1);
}

__global__ void k_norm(const int* __restrict__ cnt, float* __restrict__ norm, int N) {
    int i = blockIdx.x * blockDim.x + threadIdx.x;
    if (i < N) norm[i] = 1.0f / fmaxf((float)cnt[i], 1.0f);
}

__global__ void k_scan1(const int* __restrict__ cnt, int* __restrict__ part,
                        int* __restrict__ bsum, int N) {
    __shared__ int s[256];
    int i = blockIdx.x * 256 + threadIdx.x;
    int v = (i < N) ? cnt[i] : 0;
    s[threadIdx.x] = v; __syncthreads();
    #pragma unroll
    for (int o = 1; o < 256; o <<= 1) {
        int t = (threadIdx.x >= o) ? s[threadIdx.x - o] : 0;
        __syncthreads();
        s[threadIdx.x] += t;
        __syncthreads();
    }
    if (i < N) part[i] = s[threadIdx.x] - v;
    if (threadIdx.x == 255) bsum[blockIdx.x] = s[255];
}

__global__ void k_scan2(int* __restrict__ bsum, int nb) {
    __shared__ int s[256];
    int v = (threadIdx.x < nb) ? bsum[threadIdx.x] : 0;
    s[threadIdx.x] = v; __syncthreads();
    #pragma unroll
    for (int o = 1; o < 256; o <<= 1) {
        int t = (threadIdx.x >= o) ? s[threadIdx.x - o] : 0;
        __syncthreads();
        s[threadIdx.x] += t;
        __syncthreads();
    }
    if (threadIdx.x < nb) bsum[threadIdx.x] = s[threadIdx.x] - v;
}

__global__ void k_scan3(const int* __restrict__ part, const int* __restrict__ bsum,
                        int* __restrict__ rowptr, int* __restrict__ cursor, int N, int E) {
    int i = blockIdx.x * 256 + threadIdx.x;
    if (i < N) {
        int r = part[i] + bsum[blockIdx.x];
        rowptr[i] = r; cursor[i] = r;
    }
    if (i == 0) rowptr[N] = E;
}

__global__ void k_scatter(const int* __restrict__ src, const int* __restrict__ dst,
                          const int* __restrict__ et, int* __restrict__ cursor,
                          unsigned* __restrict__ erec, int E, int halfE) {
    int e = blockIdx.x * blockDim.x + threadIdx.x;
    if (e < E) {
        int d = dst[e];
        int pos = atomicAdd(&cursor[d], 1);
        unsigned rec = (unsigned)src[e] | ((unsigned)et[e] << 16)
                     | ((e >= halfE) ? 0x80000000u : 0u);
        erec[pos] = rec;
    }
}

// ---- dtype prep ------------------------------------------------------------

__global__ void k_cvt3(const float* __restrict__ s0, unsigned short* __restrict__ d0, long n0,
                       const float* __restrict__ s1, unsigned short* __restrict__ d1, long n1,
                       const float* __restrict__ s2, unsigned short* __restrict__ d2, long n2) {
    long i = (long)blockIdx.x * blockDim.x + threadIdx.x;
    const float* s; unsigned short* d; long j = i;
    if (j < n0) { s = s0; d = d0; }
    else {
        j -= n0;
        if (j < n1) { s = s1; d = d1; }
        else { j -= n1; if (j >= n2) return; s = s2; d = d2; }
    }
    float4 v = ((const float4*)s)[j];
    ushort4 o;
    o.x = f2b(v.x); o.y = f2b(v.y); o.z = f2b(v.z); o.w = f2b(v.w);
    ((ushort4*)d)[j] = o;
}

// Repack 7 W[256][256] (row-major f32) into MFMA-B fragment layout bf16:
// out[mi][((kg*16+nn)*64 + l)*8 + j] = W[kg*32 + (l>>4)*8 + j][nn*16 + (l&15)]
__global__ void k_wfrag7(const float* __restrict__ w0, const float* __restrict__ w1,
                         const float* __restrict__ w2, const float* __restrict__ w3,
                         const float* __restrict__ w4, const float* __restrict__ w5,
                         const float* __restrict__ w6, unsigned short* __restrict__ out) {
    int o = blockIdx.x * 256 + threadIdx.x;      // grid = 7*65536/256
    int mi = o >> 16;
    int r  = o & 65535;
    const float* W = (mi == 0) ? w0 : (mi == 1) ? w1 : (mi == 2) ? w2 :
                     (mi == 3) ? w3 : (mi == 4) ? w4 : (mi == 5) ? w5 : w6;
    int j  = r & 7;
    int l  = (r >> 3) & 63;
    int nn = (r >> 9) & 15;
    int kg = r >> 13;
    int k = kg * 32 + (l >> 4) * 8 + j;
    int n = nn * 16 + (l & 15);
    out[o] = f2b(W[k * 256 + n]);
}

// ---- CSR gather aggregation (no atomics), 4-edge software pipeline --------

__global__ __launch_bounds__(256)
void k_agg(const unsigned short* __restrict__ xb, const unsigned short* __restrict__ relb,
           const int* __restrict__ rowptr, const unsigned* __restrict__ erec,
           const float* __restrict__ norm,
           unsigned short* __restrict__ sIn, unsigned short* __restrict__ sOut,
           int N, int D)
{
    const int w = threadIdx.x >> 6, l = threadIdx.x & 63;
    const int v = blockIdx.x * 4 + w;
    if (v >= N) return;
    const int rs = rowptr[v], re = rowptr[v + 1];
    const float nm = norm[v];

    float ai0 = 0, ai1 = 0, ai2 = 0, ai3 = 0;
    float ao0 = 0, ao1 = 0, ao2 = 0, ao3 = 0;

    unsigned c0 = (rs     < re) ? erec[rs]     : 0u;
    unsigned c1 = (rs + 1 < re) ? erec[rs + 1] : 0u;
    unsigned c2 = (rs + 2 < re) ? erec[rs + 2] : 0u;
    unsigned c3 = (rs + 3 < re) ? erec[rs + 3] : 0u;
    int i = rs;
    while (i + 4 <= re) {
        unsigned m0 = (i + 4 < re) ? erec[i + 4] : 0u;
        unsigned m1 = (i + 5 < re) ? erec[i + 5] : 0u;
        unsigned m2 = (i + 6 < re) ? erec[i + 6] : 0u;
        unsigned m3 = (i + 7 < re) ? erec[i + 7] : 0u;
        ushort4 x0 = *(const ushort4*)(xb   + (size_t)(c0 & 0xffff) * D + l * 4);
        ushort4 r0 = *(const ushort4*)(relb + (size_t)((c0 >> 16) & 0x7fff) * D + l * 4);
        ushort4 x1 = *(const ushort4*)(xb   + (size_t)(c1 & 0xffff) * D + l * 4);
        ushort4 r1 = *(const ushort4*)(relb + (size_t)((c1 >> 16) & 0x7fff) * D + l * 4);
        ushort4 x2 = *(const ushort4*)(xb   + (size_t)(c2 & 0xffff) * D + l * 4);
        ushort4 r2 = *(const ushort4*)(relb + (size_t)((c2 >> 16) & 0x7fff) * D + l * 4);
        ushort4 x3 = *(const ushort4*)(xb   + (size_t)(c3 & 0xffff) * D + l * 4);
        ushort4 r3 = *(const ushort4*)(relb + (size_t)((c3 >> 16) & 0x7fff) * D + l * 4);
        float p0, p1, p2, p3;
        p0 = b2f(x0.x)*b2f(r0.x); p1 = b2f(x0.y)*b2f(r0.y);
        p2 = b2f(x0.z)*b2f(r0.z); p3 = b2f(x0.w)*b2f(r0.w);
        if (c0 >> 31) { ao0 += p0; ao1 += p1; ao2 += p2; ao3 += p3; }
        else          { ai0 += p0; ai1 += p1; ai2 += p2; ai3 += p3; }
        p0 = b2f(x1.x)*b2f(r1.x); p1 = b2f(x1.y)*b2f(r1.y);
        p2 = b2f(x1.z)*b2f(r1.z); p3 = b2f(x1.w)*b2f(r1.w);
        if (c1 >> 31) { ao0 += p0; ao1 += p1; ao2 += p2; ao3 += p3; }
        else          { ai0 += p0; ai1 += p1; ai2 += p2; ai3 += p3; }
        p0 = b2f(x2.x)*b2f(r2.x); p1 = b2f(x2.y)*b2f(r2.y);
        p2 = b2f(x2.z)*b2f(r2.z); p3 = b2f(x2.w)*b2f(r2.w);
        if (c2 >> 31) { ao0 += p0; ao1 += p1; ao2 += p2; ao3 += p3; }
        else          { ai0 += p0; ai1 += p1; ai2 += p2; ai3 += p3; }
        p0 = b2f(x3.x)*b2f(r3.x); p1 = b2f(x3.y)*b2f(r3.y);
        p2 = b2f(x3.z)*b2f(r3.z); p3 = b2f(x3.w)*b2f(r3.w);
        if (c3 >> 31) { ao0 += p0; ao1 += p1; ao2 += p2; ao3 += p3; }
        else          { ai0 += p0; ai1 += p1; ai2 += p2; ai3 += p3; }
        c0 = m0; c1 = m1; c2 = m2; c3 = m3; i += 4;
    }
    #pragma unroll
    for (int j = 0; j < 3; ++j) {
        if (i + j < re) {
            unsigned cur = (j == 0) ? c0 : (j == 1) ? c1 : c2;
            ushort4 x0 = *(const ushort4*)(xb   + (size_t)(cur & 0xffff) * D + l * 4);
            ushort4 r0 = *(const ushort4*)(relb + (size_t)((cur >> 16) & 0x7fff) * D + l * 4);
            float p0 = b2f(x0.x)*b2f(r0.x), p1 = b2f(x0.y)*b2f(r0.y);
            float p2 = b2f(x0.z)*b2f(r0.z), p3 = b2f(x0.w)*b2f(r0.w);
            if (cur >> 31) { ao0 += p0; ao1 += p1; ao2 += p2; ao3 += p3; }
            else           { ai0 += p0; ai1 += p1; ai2 += p2; ai3 += p3; }
        }
    }

    ushort4 oi, oo;
    oi.x = f2b(ai0 * nm); oi.y = f2b(ai1 * nm); oi.z = f2b(ai2 * nm); oi.w = f2b(ai3 * nm);
    oo.x = f2b(ao0 * nm); oo.y = f2b(ao1 * nm); oo.z = f2b(ao2 * nm); oo.w = f2b(ao3 * nm);
    *(ushort4*)(sIn  + (size_t)v * D + l * 4) = oi;
    *(ushort4*)(sOut + (size_t)v * D + l * 4) = oo;
}

// ---- fused node GEMM -------------------------------------------------------
// Step S: ds_write tile S+1 (A regs loaded at S-2); issue B-loads for step
// S+1 into Bn; MFMA step S from At[S&1] x Bc (regs, loaded at S-1); issue
// A-loads for tile S+3; lgkmcnt(0); s_barrier (fenced).  Vmem never drained.

#define GIT(S, AtC, AtN, Rw0, Rw1, Rl0, Rl1, Bc, Bn)                            \
  do {                                                                          \
    if ((S) + 1 < 12) {                                                         \
      *(uint4*)(&AtN[wo0]) = Rw0;                                               \
      *(uint4*)(&AtN[wo1]) = Rw1;                                               \
    }                                                                           \
    if ((S) + 1 < 12) {                                                         \
      const int pn_ = ((S) + 1) >> 2, cbn_ = ((S) + 1) & 3;                     \
      const unsigned short* __restrict__ Wn_ = Wf + (size_t)pn_ * 65536;        \
      _Pragma("unroll")                                                         \
      for (int kk_ = 0; kk_ < 2; ++kk_) {                                       \
        _Pragma("unroll")                                                       \
        for (int n_ = 0; n_ < 4; ++n_) {                                        \
          Bn[kk_ * 4 + n_] = *(const bf16x8*)(Wn_ +                             \
              ((((cbn_ * 2 + kk_) * 16 + (w * 4 + n_)) * 64 + l) * 8));         \
        }                                                                       \
      }                                                                         \
    }                                                                           \
    {                                                                           \
      const int cb_ = (S) & 3;                                                  \
      _Pragma("unroll")                                                         \
      for (int kk_ = 0; kk_ < 2; ++kk_) {                                       \
        (void)cb_;                                                              \
        bf16x8 a_[4];                                                           \
        _Pragma("unroll")                                                       \
        for (int m_ = 0; m_ < 4; ++m_) {                                        \
          int rm_ = 16 * m_ + lr;                                               \
          int ch_ = (kk_ * 4 + lq) ^ (rm_ & 7);                                 \
          a_[m_] = *(const bf16x8*)(&AtC[rm_ * 64 + ch_ * 8]);                  \
        }                                                                       \
        _Pragma("unroll")                                                       \
        for (int m_ = 0; m_ < 4; ++m_) {                                        \
          _Pragma("unroll")                                                     \
          for (int n_ = 0; n_ < 4; ++n_) {                                      \
            acc[m_][n_] = __builtin_amdgcn_mfma_f32_16x16x32_bf16(a_[m_], Bc[kk_ * 4 + n_], acc[m_][n_], 0, 0, 0); \
          }                                                                     \
        }                                                                       \
      }                                                                         \
    }                                                                           \
    if ((S) + 3 < 12) {                                                         \
      const int p3_ = ((S) + 3) >> 2, cb3_ = ((S) + 3) & 3;                     \
      const unsigned short* ap_ = (p3_ == 0) ? a0 : ((p3_ == 1) ? a1 : a2);     \
      Rl0 = *(const uint4*)(ap_ + g0 + cb3_ * 64);                              \
      Rl1 = *(const uint4*)(ap_ + g1 + cb3_ * 64);                              \
    }                                                                           \
    asm volatile("s_waitcnt lgkmcnt(0)" ::: "memory");                          \
    __builtin_amdgcn_sched_barrier(0);                                          \
    __builtin_amdgcn_s_barrier();                                               \
    __builtin_amdgcn_sched_barrier(0);                                          \
  } while (0)

template <bool HEAD>
__global__ __launch_bounds__(256, 2)
void k_gemm(const unsigned short* __restrict__ a0,
            const unsigned short* __restrict__ a1,
            const unsigned short* __restrict__ a2,
            const unsigned short* __restrict__ Wf,    // frag layout, 3*65536
            const float* __restrict__ bias,
            const float* __restrict__ resPtr,
            const unsigned short* __restrict__ WfMu,  // frag layout (HEAD)
            const float* __restrict__ mub,            // [256] (HEAD)
            float* __restrict__ outF,                 // [N,256] f32 (HEAD)
            unsigned short* __restrict__ outB,        // [N,256] bf16 (!HEAD)
            int N, int D)
{
    __shared__ unsigned short lds[HEAD ? 16384 : 8192];
    unsigned short* At0 = lds;
    unsigned short* At1 = lds + 4096;

    const int t = threadIdx.x;
    const int rBase = blockIdx.x * 64;

    const int w  = t >> 6;
    const int l  = t & 63;
    const int lr = l & 15;
    const int lq = l >> 4;

    // staging geometry
    const int rS0 = t >> 3;
    const int rS1 = rS0 + 32;
    const int cS  = t & 7;
    const int wo0 = rS0 * 64 + ((cS ^ (rS0 & 7)) * 8);
    const int wo1 = rS1 * 64 + ((cS ^ (rS1 & 7)) * 8);
    const size_t g0 = (size_t)min(rBase + rS0, N - 1) * D + cS * 8;
    const size_t g1 = (size_t)min(rBase + rS1, N - 1) * D + cS * 8;

    f32x4 acc[4][4] = {};
    uint4 Ra0, Ra1, Rb0, Rb1, Rc0, Rc1;
    bf16x8 B0[8], B1[8];

    // prologue: A tiles 0,1,2 in flight; tile 0 -> At0; B for step 0 -> B0
    Ra0 = *(const uint4*)(a0 + g0);
    Ra1 = *(const uint4*)(a0 + g1);
    Rb0 = *(const uint4*)(a0 + g0 + 64);
    Rb1 = *(const uint4*)(a0 + g1 + 64);
    Rc0 = *(const uint4*)(a0 + g0 + 128);
    Rc1 = *(const uint4*)(a0 + g1 + 128);
    #pragma unroll
    for (int kk = 0; kk < 2; ++kk) {
        #pragma unroll
        for (int n = 0; n < 4; ++n)
            B0[kk * 4 + n] = *(const bf16x8*)(Wf + (((kk * 16 + (w * 4 + n)) * 64 + l) * 8));
    }
    *(uint4*)(&At0[wo0]) = Ra0;
    *(uint4*)(&At0[wo1]) = Ra1;
    asm volatile("s_waitcnt lgkmcnt(0)" ::: "memory");
    __builtin_amdgcn_sched_barrier(0);
    __builtin_amdgcn_s_barrier();
    __builtin_amdgcn_sched_barrier(0);

    GIT(0,  At0, At1, Rb0, Rb1, Ra0, Ra1, B0, B1);
    GIT(1,  At1, At0, Rc0, Rc1, Rb0, Rb1, B1, B0);
    GIT(2,  At0, At1, Ra0, Ra1, Rc0, Rc1, B0, B1);
    GIT(3,  At1, At0, Rb0, Rb1, Ra0, Ra1, B1, B0);
    GIT(4,  At0, At1, Rc0, Rc1, Rb0, Rb1, B0, B1);
    GIT(5,  At1, At0, Ra0, Ra1, Rc0, Rc1, B1, B0);
    GIT(6,  At0, At1, Rb0, Rb1, Ra0, Ra1, B0, B1);
    GIT(7,  At1, At0, Rc0, Rc1, Rb0, Rb1, B1, B0);
    GIT(8,  At0, At1, Ra0, Ra1, Rc0, Rc1, B0, B1);
    GIT(9,  At1, At0, Rb0, Rb1, Ra0, Ra1, B1, B0);
    GIT(10, At0, At1, Rc0, Rc1, Rb0, Rb1, B0, B1);
    GIT(11, At1, At0, Ra0, Ra1, Rc0, Rc1, B1, B0);

    const int rb4 = lq * 4;
    const float resv = resPtr[0];

    if (!HEAD) {
        // ---- coalesced epilogue: stage s=res*tanh(acc+bias) in LDS halves ----
        // C is 64 rows x 128 cols bf16 per half -> 16 chunks (16B) per row.
        unsigned short* C = lds;
        #pragma unroll
        for (int half = 0; half < 2; ++half) {
            if ((w >> 1) == half) {
                #pragma unroll
                for (int m = 0; m < 4; ++m) {
                    #pragma unroll
                    for (int i = 0; i < 4; ++i) {
                        int r6 = 16 * m + rb4 + i;
                        #pragma unroll
                        for (int n = 0; n < 4; ++n) {
                            int cH = (w & 1) * 64 + lr + 16 * n;
                            float v = acc[m][n][i] + bias[half * 128 + cH];
                            C[r6 * 128 + cH] = f2b(resv * ftanh(v));
                        }
                    }
                }
            }
            __syncthreads();
            #pragma unroll
            for (int ii = 0; ii < 4; ++ii) {
                int g   = ii * 256 + t;             // 1024 chunks total
                int r   = g >> 4;                   // 16 chunks per row
                int cc  = g & 15;
                int row = rBase + r;
                if (row < N) {
                    bf16x8 sv = *(const bf16x8*)(&C[r * 128 + cc * 8]);
                    const unsigned short* ar = a0 + (size_t)row * D + half * 128 + cc * 8;
                    uint4 av = *(const uint4*)ar;
                    unsigned aw[4] = { av.x, av.y, av.z, av.w };
                    unsigned ow[4];
                    #pragma unroll
                    for (int p = 0; p < 4; ++p) {
                        float h0 = b2f((unsigned short)(aw[p] & 0xffff)) + b2f((unsigned short)sv[2 * p]);
                        float h1 = b2f((unsigned short)(aw[p] >> 16))    + b2f((unsigned short)sv[2 * p + 1]);
                        ow[p] = (unsigned)f2b(h0) | ((unsigned)f2b(h1) << 16);
                    }
                    *(uint4*)(outB + (size_t)row * D + half * 128 + cc * 8) =
                        make_uint4(ow[0], ow[1], ow[2], ow[3]);
                }
            }
            __syncthreads();
        }
    } else {
        // ---- HEAD: h2 -> swizzled LDS tile, then out = h2 @ WfMu + mub ----
        #pragma unroll
        for (int m = 0; m < 4; ++m) {
            #pragma unroll
            for (int i = 0; i < 4; ++i) {
                int row = rBase + 16 * m + rb4 + i;
                if (row < N) {
                    size_t base = (size_t)row * D + w * 64 + lr;
                    int r6 = 16 * m + rb4 + i;
                    #pragma unroll
                    for (int n = 0; n < 4; ++n) {
                        int   c = w * 64 + lr + 16 * n;
                        float v = acc[m][n][i] + bias[c];
                        float h = b2f(a0[base + 16 * n]) + resv * ftanh(v);
                        lds[r6 * 256 + (c ^ ((r6 & 7) << 3))] = f2b(h);
                    }
                }
            }
        }
        __syncthreads();
        #pragma unroll
        for (int m = 0; m < 4; ++m) {
            #pragma unroll
            for (int n = 0; n < 4; ++n)
                acc[m][n] = (f32x4){0.f, 0.f, 0.f, 0.f};
        }

        #pragma unroll
        for (int s2 = 0; s2 < 4; ++s2) {
            #pragma unroll
            for (int kk = 0; kk < 2; ++kk) {
                const int kg = s2 * 2 + kk;
                bf16x8 a_[4], b_[4];
                #pragma unroll
                for (int m = 0; m < 4; ++m) {
                    int rm = 16 * m + lr;
                    int ch = (s2 * 8 + kk * 4 + lq) ^ (rm & 7);
                    a_[m] = *(const bf16x8*)(&lds[rm * 256 + ch * 8]);
                }
                #pragma unroll
                for (int n = 0; n < 4; ++n)
                    b_[n] = *(const bf16x8*)(WfMu + (((kg * 16 + (w * 4 + n)) * 64 + l) * 8));
                #pragma unroll
                for (int m = 0; m < 4; ++m) {
                    #pragma unroll
                    for (int n = 0; n < 4; ++n)
                        acc[m][n] = __builtin_amdgcn_mfma_f32_16x16x32_bf16(a_[m], b_[n], acc[m][n], 0, 0, 0);
                }
            }
        }

        // ---- coalesced f32 store: stage acc+mub in LDS halves (64x128 f32) ----
        __syncthreads();                           // all mu-GEMM LDS reads done
        float* Cf = (float*)lds;                   // 32 KB = one 64x128 f32 half
        #pragma unroll
        for (int half = 0; half < 2; ++half) {
            if ((w >> 1) == half) {
                #pragma unroll
                for (int m = 0; m < 4; ++m) {
                    #pragma unroll
                    for (int i = 0; i < 4; ++i) {
                        int r6 = 16 * m + rb4 + i;
                        #pragma unroll
                        for (int n = 0; n < 4; ++n) {
                            int cH = (w & 1) * 64 + lr + 16 * n;
                            Cf[r6 * 128 + cH] = acc[m][n][i] + mub[half * 128 + cH];
                        }
                    }
                }
            }
            __syncthreads();
            #pragma unroll
            for (int ii = 0; ii < 8; ++ii) {
                int g   = ii * 256 + t;            // 2048 chunks total
                int r   = g >> 5;                  // 32 float4-chunks per row
                int cc  = g & 31;
                int row = rBase + r;
                if (row < N) {
                    *(float4*)(outF + (size_t)row * D + half * 128 + cc * 4) =
                        *(const float4*)(&Cf[r * 128 + cc * 4]);
                }
            }
            __syncthreads();
        }
    }
}

// ---------------------------------------------------------------------------

extern "C" void kernel_launch(void* const* d_in, const int* in_sizes, int n_in,
                              void* d_out, int out_size, void* d_ws, size_t ws_size,
                              hipStream_t stream)
{
    const float* emb  = (const float*)d_in[0];
    const int*   ei   = (const int*)  d_in[1];
    const int*   et   = (const int*)  d_in[2];
    const float* rel1 = (const float*)d_in[3];
    const float* Wi1  = (const float*)d_in[4];
    const float* Wo1  = (const float*)d_in[5];
    const float* Wl1  = (const float*)d_in[6];
    const float* b1   = (const float*)d_in[7];
    const float* rel2 = (const float*)d_in[8];
    const float* Wi2  = (const float*)d_in[9];
    const float* Wo2  = (const float*)d_in[10];
    const float* Wl2  = (const float*)d_in[11];
    const float* b2   = (const float*)d_in[12];
    const float* res  = (const float*)d_in[13];
    const float* muw  = (const float*)d_in[14];
    const float* mub  = (const float*)d_in[15];

    const int D = in_sizes[7];          // 256
    const int N = in_sizes[0] / D;      // 50000
    const int E = in_sizes[2];          // 320000
    const int R = in_sizes[3] / D;      // 400
    const int halfE = E / 2;
    const int* srcA = ei;
    const int* dstA = ei + E;
    const size_t DD = (size_t)D * D;

    char* ws = (char*)d_ws;
    size_t off = 0;
    auto alloc = [&](size_t bytes) -> char* {
        char* p = ws + off; off += (bytes + 255) & ~(size_t)255; return p;
    };
    const int nb1 = (N + 255) / 256;

    float*          norm   = (float*)          alloc((size_t)N * 4);
    int*            cnt    = (int*)            alloc((size_t)N * 4);
    int*            rowptr = (int*)            alloc((size_t)(N + 1) * 4);
    int*            cursor = (int*)            alloc((size_t)N * 4);
    int*            part   = (int*)            alloc((size_t)N * 4);
    int*            bsum   = (int*)            alloc(1024);
    unsigned*       erec   = (unsigned*)       alloc((size_t)E * 4);
    unsigned short* xb     = (unsigned short*) alloc((size_t)N * D * 2);
    unsigned short* h1b    = (unsigned short*) alloc((size_t)N * D * 2);
    unsigned short* sIn    = (unsigned short*) alloc((size_t)N * D * 2);
    unsigned short* sOut   = (unsigned short*) alloc((size_t)N * D * 2);
    unsigned short* r1b    = (unsigned short*) alloc((size_t)R * D * 2);
    unsigned short* r2b    = (unsigned short*) alloc((size_t)R * D * 2);
    unsigned short* fAll   = (unsigned short*) alloc(7 * DD * 2);
    if (off > ws_size) return;

    unsigned short* fW1 = fAll;            // [Wl1, Wi1, Wo1]
    unsigned short* fW2 = fAll + 3 * DD;   // [Wl2, Wi2, Wo2]
    unsigned short* fMu = fAll + 6 * DD;

    // --- CSR + norm ---
    hipMemsetAsync(cnt, 0, (size_t)N * 4, stream);
    k_hist   <<<(E + 255) / 256, 256, 0, stream>>>(dstA, cnt, E);
    k_norm   <<<nb1, 256, 0, stream>>>(cnt, norm, N);
    k_scan1  <<<nb1, 256, 0, stream>>>(cnt, part, bsum, N);
    k_scan2  <<<1,   256, 0, stream>>>(bsum, nb1);
    k_scan3  <<<nb1, 256, 0, stream>>>(part, bsum, rowptr, cursor, N, E);
    k_scatter<<<(E + 255) / 256, 256, 0, stream>>>(srcA, dstA, et, cursor, erec, E, halfE);

    // --- dtype prep ---
    long nd4 = (long)N * D / 4, rd4 = (long)R * D / 4;
    long tot4 = nd4 + 2 * rd4;
    k_cvt3<<<(int)((tot4 + 255) / 256), 256, 0, stream>>>(
        emb, xb, nd4, rel1, r1b, rd4, rel2, r2b, rd4);
    k_wfrag7<<<(int)(7 * DD / 256), 256, 0, stream>>>(
        Wl1, Wi1, Wo1, Wl2, Wi2, Wo2, muw, fAll);

    const int AB = (N + 3) / 4;
    const int NB = (N + 63) / 64;

    // --- layer 1 ---
    k_agg<<<AB, 256, 0, stream>>>(xb, r1b, rowptr, erec, norm, sIn, sOut, N, D);
    k_gemm<false><<<NB, 256, 0, stream>>>(xb, sIn, sOut, fW1, b1, res,
                                          nullptr, nullptr, nullptr, h1b, N, D);

    // --- layer 2 + head (fused) ---
    k_agg<<<AB, 256, 0, stream>>>(h1b, r2b, rowptr, erec, norm, sIn, sOut, N, D);
    k_gemm<true><<<NB, 256, 0, stream>>>(h1b, sIn, sOut, fW2, b2, res,
                                         fMu, mub, (float*)d_out, nullptr, N, D);
}